// Round 14
// baseline (1412.645 us; speedup 1.0000x reference)
//
#include <hip/hip_runtime.h>
#include <hip/hip_bf16.h>
#include <math.h>

#define N_NODES 51200
#define N_GRAPHS 512
#define S_NODES 100
#define N_EDGES 512000
#define HDF 256          // H*D
#define NEGF (-1e30f)
#define DCAP 128         // per-node degree cap

typedef short bf16x8 __attribute__((ext_vector_type(8)));
typedef float f32x4 __attribute__((ext_vector_type(4)));

__device__ inline unsigned short f2b(float x) {   // fp32 -> bf16 RNE
    union { float f; unsigned u; } v; v.f = x;
    unsigned r = v.u + 0x7FFFu + ((v.u >> 16) & 1u);
    return (unsigned short)(r >> 16);
}
__device__ inline float b2f(unsigned short b) {
    union { float f; unsigned u; } v; v.u = ((unsigned)b) << 16; return v.f;
}

// ---------------------------------------------------------------- util
__global__ void set_int(int* __restrict__ p, int v, int n) {
    int i = blockIdx.x * 256 + threadIdx.x;
    if (i < n) p[i] = v;
}

__global__ void init_zero(int* __restrict__ deg, int* __restrict__ cursor,
                          float* __restrict__ acc1, float* __restrict__ acc2) {
    int i = blockIdx.x * 256 + threadIdx.x;   // grid covers 262144
    if (i < N_NODES) { deg[i] = 0; cursor[i] = 0; }
    acc1[i] = 0.f;
    acc2[i] = 0.f;
}

// pre-split weights: fp32 W[K x NC] -> bf16 hi/lo in fragment layout
// element (k,c) -> [(k>>3)*NC + c]*8 + (k&7)
struct WSplitDesc { const float* W; unsigned short* Wh; unsigned short* Wl; int K, NC; };
struct WSplitPack { WSplitDesc d[12]; };
__global__ void wsplit_all(WSplitPack p) {
    WSplitDesc d = p.d[blockIdx.y];
    int idx = blockIdx.x * 256 + threadIdx.x;
    if (idx >= d.K * d.NC) return;
    int k = idx / d.NC, c = idx - k * d.NC;
    float v = d.W[idx];
    unsigned short h = f2b(v);
    int o = ((k >> 3) * d.NC + c) * 8 + (k & 7);
    d.Wh[o] = h;
    d.Wl[o] = f2b(v - b2f(h));
}

// split x0 (K=64, row-major fp32) into A-fragment hi/lo layout
__global__ void asplit64(const float* __restrict__ X,
                         unsigned short* __restrict__ Xh, unsigned short* __restrict__ Xl) {
    int idx = blockIdx.x * 256 + threadIdx.x;   // N_NODES*64
    int row = idx >> 6, k = idx & 63;
    float v = X[idx];
    unsigned short h = f2b(v);
    int o = ((k >> 3) * N_NODES + row) * 8 + (k & 7);
    Xh[o] = h;
    Xl[o] = f2b(v - b2f(h));
}

// ------------------------------------------------- barrier-free MFMA GEMM
// A and B both pre-split in global fragment layout -> each lane reads
// contiguous 16B frags; NO LDS, NO k-loop barriers, zero convert VALU.
// Top-k scale applied on OUTPUT rows: C = diag(s)*(A@B) (+bias).
// Tile 128x256, 512 thr, 8 waves (2x4). grid = (NC/256, N/128).
__global__ __launch_bounds__(512) void gemm_main(
    const unsigned short* __restrict__ Ah, const unsigned short* __restrict__ Al,
    const unsigned short* __restrict__ Bh, const unsigned short* __restrict__ Bl,
    const float* __restrict__ bias, float* __restrict__ C,
    int K, int NC,
    const float* __restrict__ rowScale, const int* __restrict__ rsMask)
{
    int row0 = blockIdx.y * 128, col0 = blockIdx.x * 256;
    int t = threadIdx.x, lane = t & 63, w = t >> 6;
    int wr = w >> 2, wc = w & 3;
    int l15 = lane & 15, l4 = lane >> 4;
    f32x4 acc[4][4];
    #pragma unroll
    for (int m = 0; m < 4; ++m)
        #pragma unroll
        for (int n = 0; n < 4; ++n) acc[m][n] = (f32x4){0.f, 0.f, 0.f, 0.f};

    for (int k0 = 0; k0 < K; k0 += 32) {
        int kg = (k0 >> 3) + l4;
        size_t arow = (size_t)kg * N_NODES;
        size_t brow = (size_t)kg * NC;
        bf16x8 ah[4], al[4], bh[4], bl[4];
        #pragma unroll
        for (int n = 0; n < 4; ++n) {
            size_t gb = (brow + col0 + wc * 64 + n * 16 + l15) * 8;
            bh[n] = *(const bf16x8*)&Bh[gb];
            bl[n] = *(const bf16x8*)&Bl[gb];
        }
        #pragma unroll
        for (int m = 0; m < 4; ++m) {
            size_t ga = (arow + row0 + wr * 64 + m * 16 + l15) * 8;
            ah[m] = *(const bf16x8*)&Ah[ga];
            al[m] = *(const bf16x8*)&Al[ga];
        }
        #pragma unroll
        for (int m = 0; m < 4; ++m)
            #pragma unroll
            for (int n = 0; n < 4; ++n) {
                acc[m][n] = __builtin_amdgcn_mfma_f32_16x16x32_bf16(ah[m], bh[n], acc[m][n], 0, 0, 0);
                acc[m][n] = __builtin_amdgcn_mfma_f32_16x16x32_bf16(ah[m], bl[n], acc[m][n], 0, 0, 0);
                acc[m][n] = __builtin_amdgcn_mfma_f32_16x16x32_bf16(al[m], bh[n], acc[m][n], 0, 0, 0);
            }
    }
    #pragma unroll
    for (int m = 0; m < 4; ++m) {
        int rbase = row0 + wr * 64 + m * 16 + l4 * 4;
        float sr[4];
        #pragma unroll
        for (int r = 0; r < 4; ++r)
            sr[r] = rowScale ? (rsMask[rbase + r] ? rowScale[rbase + r] : 0.f) : 1.f;
        #pragma unroll
        for (int n = 0; n < 4; ++n) {
            int col = col0 + wc * 64 + n * 16 + l15;
            float bv = bias ? bias[col] : 0.f;
            #pragma unroll
            for (int r = 0; r < 4; ++r)
                C[(size_t)(rbase + r) * NC + col] = sr[r] * acc[m][n][r] + bv;
        }
    }
}

// fused skip-GEMM: out = relu(s*(A@B) + agg + bias) * nmask, written as
// hi/lo A-fragments for the NEXT layer (in-place over Ah/Al is safe:
// one barrier after the k-loop; waves partition rows). grid = (1, N/128).
__global__ __launch_bounds__(512) void gemm_fused(
    const unsigned short* __restrict__ Ah, const unsigned short* __restrict__ Al,
    const unsigned short* __restrict__ Bh, const unsigned short* __restrict__ Bl,
    const float* __restrict__ bias,
    const float* __restrict__ agg, int aggStride,
    const int* __restrict__ nmaskArr,
    int K,
    const float* __restrict__ rowScale, const int* __restrict__ rsMask,
    unsigned short* __restrict__ Xh, unsigned short* __restrict__ Xl)
{
    const int NC = 256;
    int row0 = blockIdx.y * 128;
    int t = threadIdx.x, lane = t & 63, w = t >> 6;
    int wr = w >> 2, wc = w & 3;
    int l15 = lane & 15, l4 = lane >> 4;
    f32x4 acc[4][4];
    #pragma unroll
    for (int m = 0; m < 4; ++m)
        #pragma unroll
        for (int n = 0; n < 4; ++n) acc[m][n] = (f32x4){0.f, 0.f, 0.f, 0.f};

    for (int k0 = 0; k0 < K; k0 += 32) {
        int kg = (k0 >> 3) + l4;
        size_t arow = (size_t)kg * N_NODES;
        size_t brow = (size_t)kg * NC;
        bf16x8 ah[4], al[4], bh[4], bl[4];
        #pragma unroll
        for (int n = 0; n < 4; ++n) {
            size_t gb = (brow + wc * 64 + n * 16 + l15) * 8;
            bh[n] = *(const bf16x8*)&Bh[gb];
            bl[n] = *(const bf16x8*)&Bl[gb];
        }
        #pragma unroll
        for (int m = 0; m < 4; ++m) {
            size_t ga = (arow + row0 + wr * 64 + m * 16 + l15) * 8;
            ah[m] = *(const bf16x8*)&Ah[ga];
            al[m] = *(const bf16x8*)&Al[ga];
        }
        #pragma unroll
        for (int m = 0; m < 4; ++m)
            #pragma unroll
            for (int n = 0; n < 4; ++n) {
                acc[m][n] = __builtin_amdgcn_mfma_f32_16x16x32_bf16(ah[m], bh[n], acc[m][n], 0, 0, 0);
                acc[m][n] = __builtin_amdgcn_mfma_f32_16x16x32_bf16(ah[m], bl[n], acc[m][n], 0, 0, 0);
                acc[m][n] = __builtin_amdgcn_mfma_f32_16x16x32_bf16(al[m], bh[n], acc[m][n], 0, 0, 0);
            }
    }
    __syncthreads();   // all A-frag reads complete before in-place frag writes
    #pragma unroll
    for (int m = 0; m < 4; ++m) {
        int rbase = row0 + wr * 64 + m * 16 + l4 * 4;
        float sr[4], nm[4];
        #pragma unroll
        for (int r = 0; r < 4; ++r) {
            sr[r] = rowScale ? (rsMask[rbase + r] ? rowScale[rbase + r] : 0.f) : 1.f;
            nm[r] = nmaskArr[rbase + r] ? 1.f : 0.f;
        }
        #pragma unroll
        for (int n = 0; n < 4; ++n) {
            int col = wc * 64 + n * 16 + l15;
            float bv = bias[col];
            int obase = ((col >> 3) * N_NODES) * 8 + (col & 7);
            #pragma unroll
            for (int r = 0; r < 4; ++r) {
                int row = rbase + r;
                float v = fmaxf(sr[r] * acc[m][n][r] + agg[(size_t)row * aggStride + col] + bv, 0.f) * nm[r];
                int o = obase + row * 8;
                unsigned short h = f2b(v);
                Xh[o] = h;
                Xl[o] = f2b(v - b2f(h));
            }
        }
    }
}

// ---------------------------------------------------------------- CSR build
__global__ void count_deg(const int* __restrict__ dst, int* __restrict__ deg) {
    int e = blockIdx.x * 256 + threadIdx.x;
    atomicAdd(&deg[dst[e]], 1);
}

__global__ __launch_bounds__(1024) void scan_deg(const int* __restrict__ deg,
                                                 int* __restrict__ rowStart) {
    __shared__ int part[1024];
    int t = threadIdx.x;
    const int chunk = N_NODES / 1024;      // 50
    int s = t * chunk;
    int sum = 0;
    for (int i = 0; i < chunk; ++i) sum += deg[s + i];
    part[t] = sum;
    __syncthreads();
    for (int d = 1; d < 1024; d <<= 1) {
        int v = (t >= d) ? part[t - d] : 0;
        __syncthreads();
        part[t] += v;
        __syncthreads();
    }
    int excl = (t == 0) ? 0 : part[t - 1];
    for (int i = 0; i < chunk; ++i) { rowStart[s + i] = excl; excl += deg[s + i]; }
    if (t == 1023) rowStart[N_NODES] = part[1023];
}

__global__ void scatter_edges(const int* __restrict__ src, const int* __restrict__ dst,
                              int* __restrict__ cursor, const int* __restrict__ rowStart,
                              int* __restrict__ csrSrc) {
    int e = blockIdx.x * 256 + threadIdx.x;
    int d = dst[e];
    int p = atomicAdd(&cursor[d], 1);
    csrSrc[rowStart[d] + p] = src[e];
}

// ---------------------------------------------------------------- GAT pieces
__global__ __launch_bounds__(256) void gat_att_pw(const float* __restrict__ hfeat,
                                                  const float* __restrict__ att,
                                                  float* __restrict__ aS,
                                                  float* __restrict__ aD) {
    int t = threadIdx.x, w = t >> 6, l = t & 63;
    int i = blockIdx.x * 4 + w;
    int h = l >> 4, g16 = l & 15;
    float4 hv = *(const float4*)&hfeat[i * HDF + l * 4];
    float4 a0 = *(const float4*)&att[l * 4];
    float4 a1 = *(const float4*)&att[256 + l * 4];
    float p0 = hv.x * a0.x + hv.y * a0.y + hv.z * a0.z + hv.w * a0.w;
    float p1 = hv.x * a1.x + hv.y * a1.y + hv.z * a1.z + hv.w * a1.w;
    p0 += __shfl_xor(p0, 1, 64);  p1 += __shfl_xor(p1, 1, 64);
    p0 += __shfl_xor(p0, 2, 64);  p1 += __shfl_xor(p1, 2, 64);
    p0 += __shfl_xor(p0, 4, 64);  p1 += __shfl_xor(p1, 4, 64);
    p0 += __shfl_xor(p0, 8, 64);  p1 += __shfl_xor(p1, 8, 64);
    if (g16 == 0) { aS[i * 4 + h] = p0; aD[i * 4 + h] = p1; }
}

// GAT aggregation: 1 node per wave, XCD-streamed; parallel sS preload;
// (head, edge)-parallel logits. edge mask == nmask[src]; self-loop appended.
__global__ __launch_bounds__(256) void gat_edge_pg(
    const float* __restrict__ hfeat, const float* __restrict__ aS, const float* __restrict__ aD,
    const int* __restrict__ rowStart, const int* __restrict__ csrSrc,
    const int* __restrict__ nmask,
    float* __restrict__ aggOut)
{
    int bid = blockIdx.x;
    int t = threadIdx.x, w = t >> 6, l = t & 63;
    int i = (bid & 7) * (N_NODES / 8) + (bid >> 3) * 4 + w;   // XCD-streamed
    int h = l >> 4, g16 = l & 15;
    __shared__ float sL[4][4][DCAP + 8];
    __shared__ int   sS[4][DCAP + 8];
    if (!nmask[i]) {
        *(float4*)&aggOut[i * HDF + l * 4] = make_float4(0.f, 0.f, 0.f, 0.f);
        return;
    }
    int rs = rowStart[i];
    int deg = min(rowStart[i + 1] - rs, DCAP);
    for (int j = l; j < deg; j += 64) {
        int s_ = csrSrc[rs + j];
        sS[w][j] = nmask[s_] ? s_ : -1;
    }
    if (l == 0) sS[w][deg] = i;            // self loop (node alive here)
    float adh = aD[i * 4 + h];
    for (int j = g16; j < deg; j += 16) {
        int s_ = sS[w][j];
        float lg = NEGF;
        if (s_ >= 0) {
            lg = aS[s_ * 4 + h] + adh;
            lg = (lg >= 0.f) ? lg : 0.2f * lg;
        }
        sL[w][h][j] = lg;
    }
    if (g16 == (deg & 15)) {               // self-loop logit, one lane per head
        float lg = aS[i * 4 + h] + adh;
        sL[w][h][deg] = (lg >= 0.f) ? lg : 0.2f * lg;
    }
    int tot = deg + 1;
    float m = NEGF;
    for (int j = g16; j < tot; j += 16) m = fmaxf(m, sL[w][h][j]);
    m = fmaxf(m, __shfl_xor(m, 1, 64));
    m = fmaxf(m, __shfl_xor(m, 2, 64));
    m = fmaxf(m, __shfl_xor(m, 4, 64));
    m = fmaxf(m, __shfl_xor(m, 8, 64));
    float sum = 0.f;
    for (int j = g16; j < tot; j += 16) {
        float lv = sL[w][h][j];
        float e = (lv > -1e29f) ? __expf(lv - m) : 0.f;
        sL[w][h][j] = e;
        sum += e;
    }
    sum += __shfl_xor(sum, 1, 64);
    sum += __shfl_xor(sum, 2, 64);
    sum += __shfl_xor(sum, 4, 64);
    sum += __shfl_xor(sum, 8, 64);
    float inv = 1.f / fmaxf(sum, 1e-16f);
    float4 a4 = make_float4(0.f, 0.f, 0.f, 0.f);
    for (int j = 0; j < tot; ++j) {
        int s_ = sS[w][j];
        if (s_ < 0) continue;
        float a = sL[w][h][j] * inv;
        float4 v4 = *(const float4*)&hfeat[s_ * HDF + l * 4];
        a4.x += a * v4.x; a4.y += a * v4.y; a4.z += a * v4.z; a4.w += a * v4.w;
    }
    *(float4*)&aggOut[i * HDF + l * 4] = a4;
}

// GT attention: 1 node per wave, XCD-streamed; parallel sS preload.
// qkv row: [q|k|v]; agg overwrites OWN q-slot (race-free).
__global__ __launch_bounds__(256) void gt_edge_pg(
    float* __restrict__ qkv,
    const int* __restrict__ rowStart, const int* __restrict__ csrSrc,
    const int* __restrict__ nmask)
{
    int bid = blockIdx.x;
    int t = threadIdx.x, w = t >> 6, l = t & 63;
    int i = (bid & 7) * (N_NODES / 8) + (bid >> 3) * 4 + w;   // XCD-streamed
    int h = l >> 4, g16 = l & 15;
    __shared__ float sL[4][4][DCAP + 8];
    __shared__ int   sS[4][DCAP + 8];
    if (!nmask[i]) {
        *(float4*)&qkv[i * 768 + l * 4] = make_float4(0.f, 0.f, 0.f, 0.f);
        return;
    }
    int rs = rowStart[i];
    int deg = min(rowStart[i + 1] - rs, DCAP);
    for (int j = l; j < deg; j += 64) {
        int s_ = csrSrc[rs + j];
        sS[w][j] = nmask[s_] ? s_ : -1;
    }
    float4 q4 = *(const float4*)&qkv[i * 768 + l * 4];
    for (int j = 0; j < deg; ++j) {
        int s_ = sS[w][j];
        float p = 0.f;
        if (s_ >= 0) {
            float4 k4 = *(const float4*)&qkv[s_ * 768 + 256 + l * 4];
            p = q4.x * k4.x + q4.y * k4.y + q4.z * k4.z + q4.w * k4.w;
        }
        p += __shfl_xor(p, 1, 64);
        p += __shfl_xor(p, 2, 64);
        p += __shfl_xor(p, 4, 64);
        p += __shfl_xor(p, 8, 64);
        if (g16 == 0) sL[w][h][j] = (s_ >= 0) ? p * 0.125f : NEGF;
    }
    float m = NEGF;
    for (int j = g16; j < deg; j += 16) m = fmaxf(m, sL[w][h][j]);
    m = fmaxf(m, __shfl_xor(m, 1, 64));
    m = fmaxf(m, __shfl_xor(m, 2, 64));
    m = fmaxf(m, __shfl_xor(m, 4, 64));
    m = fmaxf(m, __shfl_xor(m, 8, 64));
    float sum = 0.f;
    for (int j = g16; j < deg; j += 16) {
        float lv = sL[w][h][j];
        float e = (lv > -1e29f) ? __expf(lv - m) : 0.f;
        sL[w][h][j] = e;
        sum += e;
    }
    sum += __shfl_xor(sum, 1, 64);
    sum += __shfl_xor(sum, 2, 64);
    sum += __shfl_xor(sum, 4, 64);
    sum += __shfl_xor(sum, 8, 64);
    float inv = 1.f / fmaxf(sum, 1e-16f);
    float4 a4 = make_float4(0.f, 0.f, 0.f, 0.f);
    for (int j = 0; j < deg; ++j) {
        int s_ = sS[w][j];
        if (s_ < 0) continue;
        float a = sL[w][h][j] * inv;
        float4 v4 = *(const float4*)&qkv[s_ * 768 + 512 + l * 4];
        a4.x += a * v4.x; a4.y += a * v4.y; a4.z += a * v4.z; a4.w += a * v4.w;
    }
    *(float4*)&qkv[i * 768 + l * 4] = a4;
}

// ---------------------------------------------------- fused score+pool+readout
// reads layer output from hi/lo fragments (x = b2f(h)+b2f(l) — identical to
// what the next GEMM's MFMA consumes).
__global__ __launch_bounds__(256) void spr_kernel(
    const unsigned short* __restrict__ Xh, const unsigned short* __restrict__ Xl,
    const float* __restrict__ w,
    float* __restrict__ score, int* __restrict__ nmask, float* __restrict__ acc)
{
    int g = blockIdx.x, t = threadIdx.x;
    int wv = t >> 6, l = t & 63;
    __shared__ float sW[256];
    __shared__ float sRaw[104];
    __shared__ float sFin[104];
    __shared__ int   sKeep[104];
    __shared__ float swn;
    __shared__ int cnt_s;
    if (t == 0) cnt_s = 0;
    sW[t] = w[t];
    __syncthreads();
    if (wv == 0) {
        float dw = 0.f;
        #pragma unroll
        for (int c = 0; c < 4; ++c) { float v = sW[l + c * 64]; dw += v * v; }
        #pragma unroll
        for (int o = 32; o > 0; o >>= 1) dw += __shfl_down(dw, o, 64);
        if (l == 0) swn = sqrtf(dw);
    }
    int base = g * S_NODES;
    for (int u = 0; u < 25; ++u) {
        int nl = wv * 25 + u;
        int row = base + nl;
        float dx = 0.f;
        #pragma unroll
        for (int c = 0; c < 4; ++c) {
            int cc = l + c * 64;
            int a = ((cc >> 3) * N_NODES + row) * 8 + (cc & 7);
            float xv = b2f(Xh[a]) + b2f(Xl[a]);
            dx += xv * sW[cc];
        }
        #pragma unroll
        for (int o = 32; o > 0; o >>= 1) dx += __shfl_down(dx, o, 64);
        if (l == 0) sRaw[nl] = dx;
    }
    __syncthreads();
    int alive = 0;
    float ck = -2.0f;
    if (t < S_NODES) {
        float sc = tanhf(sRaw[t] / swn);
        sFin[t] = sc;
        score[base + t] = sc;
        alive = nmask[base + t];
        ck = alive ? sc : -1.5f;
        sRaw[t] = ck;
        if (alive) atomicAdd(&cnt_s, 1);
    }
    __syncthreads();
    int k = (int)ceilf(0.8f * (float)cnt_s);
    if (t < S_NODES) {
        int rank = 0;
        for (int jj = 0; jj < S_NODES; ++jj) {
            float o = sRaw[jj];
            rank += (o > ck || (o == ck && jj < t)) ? 1 : 0;
        }
        int kp = (alive && rank < k) ? 1 : 0;
        sKeep[t] = kp;
        nmask[base + t] = kp;
    }
    __syncthreads();
    int tbase = ((t >> 3) * N_NODES) * 8 + (t & 7);
    float mx = NEGF, sm = 0.f, cnt = 0.f;
    for (int o = 0; o < S_NODES; o += 4) {
        int a0 = tbase + (base + o + 0) * 8;
        int a1 = tbase + (base + o + 1) * 8;
        int a2 = tbase + (base + o + 2) * 8;
        int a3 = tbase + (base + o + 3) * 8;
        float v0 = b2f(Xh[a0]) + b2f(Xl[a0]);
        float v1 = b2f(Xh[a1]) + b2f(Xl[a1]);
        float v2 = b2f(Xh[a2]) + b2f(Xl[a2]);
        float v3 = b2f(Xh[a3]) + b2f(Xl[a3]);
        if (sKeep[o + 0]) { float v = v0 * sFin[o + 0]; mx = fmaxf(mx, v); sm += v; cnt += 1.f; }
        if (sKeep[o + 1]) { float v = v1 * sFin[o + 1]; mx = fmaxf(mx, v); sm += v; cnt += 1.f; }
        if (sKeep[o + 2]) { float v = v2 * sFin[o + 2]; mx = fmaxf(mx, v); sm += v; cnt += 1.f; }
        if (sKeep[o + 3]) { float v = v3 * sFin[o + 3]; mx = fmaxf(mx, v); sm += v; cnt += 1.f; }
    }
    acc[(size_t)g * 512 + t] += mx;
    acc[(size_t)g * 512 + 256 + t] += sm / fmaxf(cnt, 1.f);
}

// ---------------------------------------------------------------- MLP head
__global__ __launch_bounds__(128) void mlp_kernel(
    const float* __restrict__ acc1, const float* __restrict__ acc2,
    const float* __restrict__ W1, const float* __restrict__ b1,
    const float* __restrict__ W2, const float* __restrict__ b2,
    const float* __restrict__ W3, const float* __restrict__ b3,
    float* __restrict__ out)
{
    int g = blockIdx.x, t = threadIdx.x;
    __shared__ float hrow[1024];
    __shared__ float h1s[128];
    __shared__ float h2s[64];
    __shared__ float o3[10];
    for (int j = t; j < 512; j += 128) {
        hrow[j] = acc1[(size_t)g * 512 + j];
        hrow[512 + j] = acc2[(size_t)g * 512 + j];
    }
    __syncthreads();
    float s = b1[t];
    for (int kx = 0; kx < 1024; ++kx) s += hrow[kx] * W1[(size_t)kx * 128 + t];
    h1s[t] = fmaxf(s, 0.f);
    __syncthreads();
    if (t < 64) {
        float s2 = b2[t];
        for (int kx = 0; kx < 128; ++kx) s2 += h1s[kx] * W2[kx * 64 + t];
        h2s[t] = fmaxf(s2, 0.f);
    }
    __syncthreads();
    if (t < 10) {
        float s3 = b3[t];
        for (int kx = 0; kx < 64; ++kx) s3 += h2s[kx] * W3[kx * 10 + t];
        o3[t] = s3;
    }
    __syncthreads();
    if (t < 10) {
        float m = o3[0];
        for (int j = 1; j < 10; ++j) m = fmaxf(m, o3[j]);
        float se = 0.f;
        for (int j = 0; j < 10; ++j) se += expf(o3[j] - m);
        out[g * 10 + t] = o3[t] - m - logf(se);
    }
}

// ---------------------------------------------------------------- launch
extern "C" void kernel_launch(void* const* d_in, const int* in_sizes, int n_in,
                              void* d_out, int out_size, void* d_ws, size_t ws_size,
                              hipStream_t stream) {
    (void)n_in; (void)out_size; (void)ws_size;
    const float* x0 = (const float*)d_in[0];
    const int* src = (const int*)d_in[1];
    const int* dst = src + N_EDGES;

    bool dictOrder = (in_sizes[7] == 64 * 768);
    const float *gatW[3], *gatAtt[3], *gatB[3], *gatRes[3];
    const float *gtWqkv[3], *gtBqkv[3], *gtWskip[3], *gtBskip[3];
    const float *gatPool, *gtPool;
    if (dictOrder) {
        for (int l = 0; l < 3; ++l) {
            int b = 3 + l * 8;
            gatW[l]    = (const float*)d_in[b + 0];
            gatAtt[l]  = (const float*)d_in[b + 1];
            gatB[l]    = (const float*)d_in[b + 2];
            gatRes[l]  = (const float*)d_in[b + 3];
            gtWqkv[l]  = (const float*)d_in[b + 4];
            gtBqkv[l]  = (const float*)d_in[b + 5];
            gtWskip[l] = (const float*)d_in[b + 6];
            gtBskip[l] = (const float*)d_in[b + 7];
        }
        gatPool = (const float*)d_in[27];
        gtPool  = (const float*)d_in[28];
    } else {
        for (int l = 0; l < 3; ++l) {
            int b = 3 + l * 4;
            gatW[l]   = (const float*)d_in[b + 0];
            gatAtt[l] = (const float*)d_in[b + 1];
            gatB[l]   = (const float*)d_in[b + 2];
            gatRes[l] = (const float*)d_in[b + 3];
            int c = 16 + l * 4;
            gtWqkv[l]  = (const float*)d_in[c + 0];
            gtBqkv[l]  = (const float*)d_in[c + 1];
            gtWskip[l] = (const float*)d_in[c + 2];
            gtBskip[l] = (const float*)d_in[c + 3];
        }
        gatPool = (const float*)d_in[15];
        gtPool  = (const float*)d_in[28];
    }
    const float* lin1W = (const float*)d_in[29];
    const float* lin1b = (const float*)d_in[30];
    const float* lin2W = (const float*)d_in[31];
    const float* lin2b = (const float*)d_in[32];
    const float* lin3W = (const float*)d_in[33];
    const float* lin3b = (const float*)d_in[34];

    char* wsp = (char*)d_ws;
    size_t off = 0;
    auto carve = [&](size_t bytes) -> void* {
        void* p = wsp + off;
        off += (bytes + 255) & ~(size_t)255;
        return p;
    };
    float* bufH   = (float*)carve((size_t)N_NODES * 768 * 4);       // 157.3 MB
    unsigned short* Xh = (unsigned short*)carve((size_t)N_NODES * 256 * 2);  // 26.2 MB
    unsigned short* Xl = (unsigned short*)carve((size_t)N_NODES * 256 * 2);  // 26.2 MB
    float* aS     = (float*)carve((size_t)N_NODES * 4 * 4);
    float* aD     = (float*)carve((size_t)N_NODES * 4 * 4);
    float* scoreB = (float*)carve((size_t)N_NODES * 4);
    int* nmask    = (int*)carve((size_t)N_NODES * 4);
    int* deg      = (int*)carve((size_t)N_NODES * 4);
    int* rowStart = (int*)carve((size_t)(N_NODES + 1) * 4);
    int* cursor   = (int*)carve((size_t)N_NODES * 4);
    int* csrSrc   = (int*)carve((size_t)N_EDGES * 4);
    float* acc1   = (float*)carve((size_t)N_GRAPHS * 512 * 4);
    float* acc2   = (float*)carve((size_t)N_GRAPHS * 512 * 4);
    const int wElems = 884736;
    unsigned short* whBase = (unsigned short*)carve((size_t)wElems * 2);
    unsigned short* wlBase = (unsigned short*)carve((size_t)wElems * 2);
    float* ysec   = bufH + (size_t)N_NODES * HDF;   // spare 2nd third (GAT agg)

    // single packed weight-split launch
    unsigned short *WH[12], *WL[12];
    {
        WSplitPack pack;
        int o = 0, maxSz = 0;
        for (int l = 0; l < 3; ++l) {
            int fi = (l == 0) ? 64 : 256;
            int sz[4] = {fi * 256, fi * 256, fi * 768, fi * 256};
            const float* Wp[4] = {gatW[l], gatRes[l], gtWqkv[l], gtWskip[l]};
            int NCs[4] = {256, 256, 768, 256};
            for (int q = 0; q < 4; ++q) {
                int idx = l * 4 + q;
                WH[idx] = whBase + o;
                WL[idx] = wlBase + o;
                pack.d[idx] = {Wp[q], WH[idx], WL[idx], fi, NCs[q]};
                if (sz[q] > maxSz) maxSz = sz[q];
                o += sz[q];
            }
        }
        wsplit_all<<<dim3((maxSz + 255) / 256, 12), 256, 0, stream>>>(pack);
    }

    init_zero<<<(N_GRAPHS * 512) / 256, 256, 0, stream>>>(deg, cursor, acc1, acc2);
    count_deg<<<N_EDGES / 256, 256, 0, stream>>>(dst, deg);
    scan_deg<<<1, 1024, 0, stream>>>(deg, rowStart);
    scatter_edges<<<N_EDGES / 256, 256, 0, stream>>>(src, dst, cursor, rowStart, csrSrc);

    for (int br = 0; br < 2; ++br) {
        bool isGAT = (br == 0);
        float* acc = isGAT ? acc1 : acc2;
        const float* poolW = isGAT ? gatPool : gtPool;
        set_int<<<N_NODES / 256, 256, 0, stream>>>(nmask, 1, N_NODES);
        asplit64<<<(N_NODES * 64) / 256, 256, 0, stream>>>(x0, Xh, Xl);
        int fi = 64;
        for (int l = 0; l < 3; ++l) {
            const float* rs = (l == 0) ? nullptr : scoreB;
            const int* rsm = (l == 0) ? nullptr : nmask;
            if (isGAT) {
                gemm_main<<<dim3(1, N_NODES / 128), 512, 0, stream>>>(
                    Xh, Xl, WH[l * 4 + 0], WL[l * 4 + 0], nullptr, bufH, fi, 256, rs, rsm);
                gat_att_pw<<<N_NODES / 4, 256, 0, stream>>>(bufH, gatAtt[l], aS, aD);
                gat_edge_pg<<<N_NODES / 4, 256, 0, stream>>>(bufH, aS, aD, rowStart,
                                                             csrSrc, nmask, ysec);
                gemm_fused<<<dim3(1, N_NODES / 128), 512, 0, stream>>>(
                    Xh, Xl, WH[l * 4 + 1], WL[l * 4 + 1], gatB[l], ysec, HDF,
                    nmask, fi, rs, rsm, Xh, Xl);
            } else {
                gemm_main<<<dim3(3, N_NODES / 128), 512, 0, stream>>>(
                    Xh, Xl, WH[l * 4 + 2], WL[l * 4 + 2], gtBqkv[l], bufH, fi, 768, rs, rsm);
                gt_edge_pg<<<N_NODES / 4, 256, 0, stream>>>(bufH, rowStart, csrSrc, nmask);
                gemm_fused<<<dim3(1, N_NODES / 128), 512, 0, stream>>>(
                    Xh, Xl, WH[l * 4 + 3], WL[l * 4 + 3], gtBskip[l], bufH /*q-slots*/, 768,
                    nmask, fi, rs, rsm, Xh, Xl);
            }
            spr_kernel<<<N_GRAPHS, 256, 0, stream>>>(Xh, Xl, poolW + l * HDF,
                                                     scoreB, nmask, acc);
            fi = HDF;
        }
    }
    mlp_kernel<<<N_GRAPHS, 128, 0, stream>>>(acc1, acc2, lin1W, lin1b, lin2W, lin2b,
                                             lin3W, lin3b, (float*)d_out);
}

// Round 15
// 1410.783 us; speedup vs baseline: 1.0013x; 1.0013x over previous
//
#include <hip/hip_runtime.h>
#include <hip/hip_bf16.h>
#include <math.h>

#define N_NODES 51200
#define N_GRAPHS 512
#define S_NODES 100
#define N_EDGES 512000
#define HDF 256          // H*D
#define NEGF (-1e30f)
#define DCAP 128         // per-node degree cap

typedef short bf16x8 __attribute__((ext_vector_type(8)));
typedef float f32x4 __attribute__((ext_vector_type(4)));

__device__ inline unsigned short f2b(float x) {   // fp32 -> bf16 RNE
    union { float f; unsigned u; } v; v.f = x;
    unsigned r = v.u + 0x7FFFu + ((v.u >> 16) & 1u);
    return (unsigned short)(r >> 16);
}
__device__ inline float b2f(unsigned short b) {
    union { float f; unsigned u; } v; v.u = ((unsigned)b) << 16; return v.f;
}

// ---------------------------------------------------------------- util
__global__ void set_int(int* __restrict__ p, int v, int n) {
    int i = blockIdx.x * 256 + threadIdx.x;
    if (i < n) p[i] = v;
}

__global__ void init_zero(int* __restrict__ deg, int* __restrict__ cursor,
                          float* __restrict__ acc1, float* __restrict__ acc2) {
    int i = blockIdx.x * 256 + threadIdx.x;   // grid covers 262144
    if (i < N_NODES) { deg[i] = 0; cursor[i] = 0; }
    acc1[i] = 0.f;
    acc2[i] = 0.f;
}

// pre-split weights: fp32 W[K x NC] -> bf16 hi/lo in fragment layout
// element (k,c) -> [(k>>3)*NC + c]*8 + (k&7)
struct WSplitDesc { const float* W; unsigned short* Wh; unsigned short* Wl; int K, NC; };
struct WSplitPack { WSplitDesc d[12]; };
__global__ void wsplit_all(WSplitPack p) {
    WSplitDesc d = p.d[blockIdx.y];
    int idx = blockIdx.x * 256 + threadIdx.x;
    if (idx >= d.K * d.NC) return;
    int k = idx / d.NC, c = idx - k * d.NC;
    float v = d.W[idx];
    unsigned short h = f2b(v);
    int o = ((k >> 3) * d.NC + c) * 8 + (k & 7);
    d.Wh[o] = h;
    d.Wl[o] = f2b(v - b2f(h));
}

// split x0 (K=64, row-major fp32) into A-fragment hi/lo layout
__global__ void asplit64(const float* __restrict__ X,
                         unsigned short* __restrict__ Xh, unsigned short* __restrict__ Xl) {
    int idx = blockIdx.x * 256 + threadIdx.x;   // N_NODES*64
    int row = idx >> 6, k = idx & 63;
    float v = X[idx];
    unsigned short h = f2b(v);
    int o = ((k >> 3) * N_NODES + row) * 8 + (k & 7);
    Xh[o] = h;
    Xl[o] = f2b(v - b2f(h));
}

// ------------------------------------------------- barrier-free MFMA GEMM
// A and B both pre-split in global fragment layout -> each lane reads
// contiguous 16B frags; NO LDS, NO k-loop barriers, zero convert VALU.
// Top-k scale applied on OUTPUT rows: C = diag(s)*(A@B) (+bias).
// Tile 128x256, 512 thr, 8 waves (2x4). grid = (NC/256, N/128).
__global__ __launch_bounds__(512) void gemm_main(
    const unsigned short* __restrict__ Ah, const unsigned short* __restrict__ Al,
    const unsigned short* __restrict__ Bh, const unsigned short* __restrict__ Bl,
    const float* __restrict__ bias, float* __restrict__ C,
    int K, int NC,
    const float* __restrict__ rowScale, const int* __restrict__ rsMask)
{
    int row0 = blockIdx.y * 128, col0 = blockIdx.x * 256;
    int t = threadIdx.x, lane = t & 63, w = t >> 6;
    int wr = w >> 2, wc = w & 3;
    int l15 = lane & 15, l4 = lane >> 4;
    f32x4 acc[4][4];
    #pragma unroll
    for (int m = 0; m < 4; ++m)
        #pragma unroll
        for (int n = 0; n < 4; ++n) acc[m][n] = (f32x4){0.f, 0.f, 0.f, 0.f};

    for (int k0 = 0; k0 < K; k0 += 32) {
        int kg = (k0 >> 3) + l4;
        size_t arow = (size_t)kg * N_NODES;
        size_t brow = (size_t)kg * NC;
        bf16x8 ah[4], al[4], bh[4], bl[4];
        #pragma unroll
        for (int n = 0; n < 4; ++n) {
            size_t gb = (brow + col0 + wc * 64 + n * 16 + l15) * 8;
            bh[n] = *(const bf16x8*)&Bh[gb];
            bl[n] = *(const bf16x8*)&Bl[gb];
        }
        #pragma unroll
        for (int m = 0; m < 4; ++m) {
            size_t ga = (arow + row0 + wr * 64 + m * 16 + l15) * 8;
            ah[m] = *(const bf16x8*)&Ah[ga];
            al[m] = *(const bf16x8*)&Al[ga];
        }
        #pragma unroll
        for (int m = 0; m < 4; ++m)
            #pragma unroll
            for (int n = 0; n < 4; ++n) {
                acc[m][n] = __builtin_amdgcn_mfma_f32_16x16x32_bf16(ah[m], bh[n], acc[m][n], 0, 0, 0);
                acc[m][n] = __builtin_amdgcn_mfma_f32_16x16x32_bf16(ah[m], bl[n], acc[m][n], 0, 0, 0);
                acc[m][n] = __builtin_amdgcn_mfma_f32_16x16x32_bf16(al[m], bh[n], acc[m][n], 0, 0, 0);
            }
    }
    #pragma unroll
    for (int m = 0; m < 4; ++m) {
        int rbase = row0 + wr * 64 + m * 16 + l4 * 4;
        float sr[4];
        #pragma unroll
        for (int r = 0; r < 4; ++r)
            sr[r] = rowScale ? (rsMask[rbase + r] ? rowScale[rbase + r] : 0.f) : 1.f;
        #pragma unroll
        for (int n = 0; n < 4; ++n) {
            int col = col0 + wc * 64 + n * 16 + l15;
            float bv = bias ? bias[col] : 0.f;
            #pragma unroll
            for (int r = 0; r < 4; ++r)
                C[(size_t)(rbase + r) * NC + col] = sr[r] * acc[m][n][r] + bv;
        }
    }
}

// fused skip-GEMM: out = relu(s*(A@B) + agg + bias) * nmask, written as
// hi/lo A-fragments for the NEXT layer (in-place over Ah/Al is safe:
// one barrier after the k-loop; waves partition rows). grid = (1, N/128).
__global__ __launch_bounds__(512) void gemm_fused(
    const unsigned short* __restrict__ Ah, const unsigned short* __restrict__ Al,
    const unsigned short* __restrict__ Bh, const unsigned short* __restrict__ Bl,
    const float* __restrict__ bias,
    const float* __restrict__ agg, int aggStride,
    const int* __restrict__ nmaskArr,
    int K,
    const float* __restrict__ rowScale, const int* __restrict__ rsMask,
    unsigned short* __restrict__ Xh, unsigned short* __restrict__ Xl)
{
    const int NC = 256;
    int row0 = blockIdx.y * 128;
    int t = threadIdx.x, lane = t & 63, w = t >> 6;
    int wr = w >> 2, wc = w & 3;
    int l15 = lane & 15, l4 = lane >> 4;
    f32x4 acc[4][4];
    #pragma unroll
    for (int m = 0; m < 4; ++m)
        #pragma unroll
        for (int n = 0; n < 4; ++n) acc[m][n] = (f32x4){0.f, 0.f, 0.f, 0.f};

    for (int k0 = 0; k0 < K; k0 += 32) {
        int kg = (k0 >> 3) + l4;
        size_t arow = (size_t)kg * N_NODES;
        size_t brow = (size_t)kg * NC;
        bf16x8 ah[4], al[4], bh[4], bl[4];
        #pragma unroll
        for (int n = 0; n < 4; ++n) {
            size_t gb = (brow + wc * 64 + n * 16 + l15) * 8;
            bh[n] = *(const bf16x8*)&Bh[gb];
            bl[n] = *(const bf16x8*)&Bl[gb];
        }
        #pragma unroll
        for (int m = 0; m < 4; ++m) {
            size_t ga = (arow + row0 + wr * 64 + m * 16 + l15) * 8;
            ah[m] = *(const bf16x8*)&Ah[ga];
            al[m] = *(const bf16x8*)&Al[ga];
        }
        #pragma unroll
        for (int m = 0; m < 4; ++m)
            #pragma unroll
            for (int n = 0; n < 4; ++n) {
                acc[m][n] = __builtin_amdgcn_mfma_f32_16x16x32_bf16(ah[m], bh[n], acc[m][n], 0, 0, 0);
                acc[m][n] = __builtin_amdgcn_mfma_f32_16x16x32_bf16(ah[m], bl[n], acc[m][n], 0, 0, 0);
                acc[m][n] = __builtin_amdgcn_mfma_f32_16x16x32_bf16(al[m], bh[n], acc[m][n], 0, 0, 0);
            }
    }
    __syncthreads();   // all A-frag reads complete before in-place frag writes
    #pragma unroll
    for (int m = 0; m < 4; ++m) {
        int rbase = row0 + wr * 64 + m * 16 + l4 * 4;
        float sr[4], nm[4];
        #pragma unroll
        for (int r = 0; r < 4; ++r) {
            sr[r] = rowScale ? (rsMask[rbase + r] ? rowScale[rbase + r] : 0.f) : 1.f;
            nm[r] = nmaskArr[rbase + r] ? 1.f : 0.f;
        }
        #pragma unroll
        for (int n = 0; n < 4; ++n) {
            int col = wc * 64 + n * 16 + l15;
            float bv = bias[col];
            int obase = ((col >> 3) * N_NODES) * 8 + (col & 7);
            #pragma unroll
            for (int r = 0; r < 4; ++r) {
                int row = rbase + r;
                float v = fmaxf(sr[r] * acc[m][n][r] + agg[(size_t)row * aggStride + col] + bv, 0.f) * nm[r];
                int o = obase + row * 8;
                unsigned short h = f2b(v);
                Xh[o] = h;
                Xl[o] = f2b(v - b2f(h));
            }
        }
    }
}

// ---------------------------------------------------------------- CSR build
__global__ void count_deg(const int* __restrict__ dst, int* __restrict__ deg) {
    int e = blockIdx.x * 256 + threadIdx.x;
    atomicAdd(&deg[dst[e]], 1);
}

__global__ __launch_bounds__(1024) void scan_deg(const int* __restrict__ deg,
                                                 int* __restrict__ rowStart) {
    __shared__ int part[1024];
    int t = threadIdx.x;
    const int chunk = N_NODES / 1024;      // 50
    int s = t * chunk;
    int sum = 0;
    for (int i = 0; i < chunk; ++i) sum += deg[s + i];
    part[t] = sum;
    __syncthreads();
    for (int d = 1; d < 1024; d <<= 1) {
        int v = (t >= d) ? part[t - d] : 0;
        __syncthreads();
        part[t] += v;
        __syncthreads();
    }
    int excl = (t == 0) ? 0 : part[t - 1];
    for (int i = 0; i < chunk; ++i) { rowStart[s + i] = excl; excl += deg[s + i]; }
    if (t == 1023) rowStart[N_NODES] = part[1023];
}

__global__ void scatter_edges(const int* __restrict__ src, const int* __restrict__ dst,
                              int* __restrict__ cursor, const int* __restrict__ rowStart,
                              int* __restrict__ csrSrc) {
    int e = blockIdx.x * 256 + threadIdx.x;
    int d = dst[e];
    int p = atomicAdd(&cursor[d], 1);
    csrSrc[rowStart[d] + p] = src[e];
}

// ---------------------------------------------------------------- GAT pieces
__global__ __launch_bounds__(256) void gat_att_pw(const float* __restrict__ hfeat,
                                                  const float* __restrict__ att,
                                                  float* __restrict__ aS,
                                                  float* __restrict__ aD) {
    int t = threadIdx.x, w = t >> 6, l = t & 63;
    int i = blockIdx.x * 4 + w;
    int h = l >> 4, g16 = l & 15;
    float4 hv = *(const float4*)&hfeat[i * HDF + l * 4];
    float4 a0 = *(const float4*)&att[l * 4];
    float4 a1 = *(const float4*)&att[256 + l * 4];
    float p0 = hv.x * a0.x + hv.y * a0.y + hv.z * a0.z + hv.w * a0.w;
    float p1 = hv.x * a1.x + hv.y * a1.y + hv.z * a1.z + hv.w * a1.w;
    p0 += __shfl_xor(p0, 1, 64);  p1 += __shfl_xor(p1, 1, 64);
    p0 += __shfl_xor(p0, 2, 64);  p1 += __shfl_xor(p1, 2, 64);
    p0 += __shfl_xor(p0, 4, 64);  p1 += __shfl_xor(p1, 4, 64);
    p0 += __shfl_xor(p0, 8, 64);  p1 += __shfl_xor(p1, 8, 64);
    if (g16 == 0) { aS[i * 4 + h] = p0; aD[i * 4 + h] = p1; }
}

// GAT aggregation: 1 node per wave, XCD-streamed; parallel sS preload;
// (head, edge)-parallel logits. edge mask == nmask[src]; self-loop appended.
__global__ __launch_bounds__(256) void gat_edge_pg(
    const float* __restrict__ hfeat, const float* __restrict__ aS, const float* __restrict__ aD,
    const int* __restrict__ rowStart, const int* __restrict__ csrSrc,
    const int* __restrict__ nmask,
    float* __restrict__ aggOut)
{
    int bid = blockIdx.x;
    int t = threadIdx.x, w = t >> 6, l = t & 63;
    int i = (bid & 7) * (N_NODES / 8) + (bid >> 3) * 4 + w;   // XCD-streamed
    int h = l >> 4, g16 = l & 15;
    __shared__ float sL[4][4][DCAP + 8];
    __shared__ int   sS[4][DCAP + 8];
    if (!nmask[i]) {
        *(float4*)&aggOut[i * HDF + l * 4] = make_float4(0.f, 0.f, 0.f, 0.f);
        return;
    }
    int rs = rowStart[i];
    int deg = min(rowStart[i + 1] - rs, DCAP);
    for (int j = l; j < deg; j += 64) {
        int s_ = csrSrc[rs + j];
        sS[w][j] = nmask[s_] ? s_ : -1;
    }
    if (l == 0) sS[w][deg] = i;            // self loop (node alive here)
    float adh = aD[i * 4 + h];
    for (int j = g16; j < deg; j += 16) {
        int s_ = sS[w][j];
        float lg = NEGF;
        if (s_ >= 0) {
            lg = aS[s_ * 4 + h] + adh;
            lg = (lg >= 0.f) ? lg : 0.2f * lg;
        }
        sL[w][h][j] = lg;
    }
    if (g16 == (deg & 15)) {               // self-loop logit, one lane per head
        float lg = aS[i * 4 + h] + adh;
        sL[w][h][deg] = (lg >= 0.f) ? lg : 0.2f * lg;
    }
    int tot = deg + 1;
    float m = NEGF;
    for (int j = g16; j < tot; j += 16) m = fmaxf(m, sL[w][h][j]);
    m = fmaxf(m, __shfl_xor(m, 1, 64));
    m = fmaxf(m, __shfl_xor(m, 2, 64));
    m = fmaxf(m, __shfl_xor(m, 4, 64));
    m = fmaxf(m, __shfl_xor(m, 8, 64));
    float sum = 0.f;
    for (int j = g16; j < tot; j += 16) {
        float lv = sL[w][h][j];
        float e = (lv > -1e29f) ? __expf(lv - m) : 0.f;
        sL[w][h][j] = e;
        sum += e;
    }
    sum += __shfl_xor(sum, 1, 64);
    sum += __shfl_xor(sum, 2, 64);
    sum += __shfl_xor(sum, 4, 64);
    sum += __shfl_xor(sum, 8, 64);
    float inv = 1.f / fmaxf(sum, 1e-16f);
    float4 a4 = make_float4(0.f, 0.f, 0.f, 0.f);
    for (int j = 0; j < tot; ++j) {
        int s_ = sS[w][j];
        if (s_ < 0) continue;
        float a = sL[w][h][j] * inv;
        float4 v4 = *(const float4*)&hfeat[s_ * HDF + l * 4];
        a4.x += a * v4.x; a4.y += a * v4.y; a4.z += a * v4.z; a4.w += a * v4.w;
    }
    *(float4*)&aggOut[i * HDF + l * 4] = a4;
}

// GT attention: 1 node per wave, XCD-streamed; parallel sS preload.
// qkv row: [q|k|v]; agg overwrites OWN q-slot (race-free).
__global__ __launch_bounds__(256) void gt_edge_pg(
    float* __restrict__ qkv,
    const int* __restrict__ rowStart, const int* __restrict__ csrSrc,
    const int* __restrict__ nmask)
{
    int bid = blockIdx.x;
    int t = threadIdx.x, w = t >> 6, l = t & 63;
    int i = (bid & 7) * (N_NODES / 8) + (bid >> 3) * 4 + w;   // XCD-streamed
    int h = l >> 4, g16 = l & 15;
    __shared__ float sL[4][4][DCAP + 8];
    __shared__ int   sS[4][DCAP + 8];
    if (!nmask[i]) {
        *(float4*)&qkv[i * 768 + l * 4] = make_float4(0.f, 0.f, 0.f, 0.f);
        return;
    }
    int rs = rowStart[i];
    int deg = min(rowStart[i + 1] - rs, DCAP);
    for (int j = l; j < deg; j += 64) {
        int s_ = csrSrc[rs + j];
        sS[w][j] = nmask[s_] ? s_ : -1;
    }
    float4 q4 = *(const float4*)&qkv[i * 768 + l * 4];
    for (int j = 0; j < deg; ++j) {
        int s_ = sS[w][j];
        float p = 0.f;
        if (s_ >= 0) {
            float4 k4 = *(const float4*)&qkv[s_ * 768 + 256 + l * 4];
            p = q4.x * k4.x + q4.y * k4.y + q4.z * k4.z + q4.w * k4.w;
        }
        p += __shfl_xor(p, 1, 64);
        p += __shfl_xor(p, 2, 64);
        p += __shfl_xor(p, 4, 64);
        p += __shfl_xor(p, 8, 64);
        if (g16 == 0) sL[w][h][j] = (s_ >= 0) ? p * 0.125f : NEGF;
    }
    float m = NEGF;
    for (int j = g16; j < deg; j += 16) m = fmaxf(m, sL[w][h][j]);
    m = fmaxf(m, __shfl_xor(m, 1, 64));
    m = fmaxf(m, __shfl_xor(m, 2, 64));
    m = fmaxf(m, __shfl_xor(m, 4, 64));
    m = fmaxf(m, __shfl_xor(m, 8, 64));
    float sum = 0.f;
    for (int j = g16; j < deg; j += 16) {
        float lv = sL[w][h][j];
        float e = (lv > -1e29f) ? __expf(lv - m) : 0.f;
        sL[w][h][j] = e;
        sum += e;
    }
    sum += __shfl_xor(sum, 1, 64);
    sum += __shfl_xor(sum, 2, 64);
    sum += __shfl_xor(sum, 4, 64);
    sum += __shfl_xor(sum, 8, 64);
    float inv = 1.f / fmaxf(sum, 1e-16f);
    float4 a4 = make_float4(0.f, 0.f, 0.f, 0.f);
    for (int j = 0; j < deg; ++j) {
        int s_ = sS[w][j];
        if (s_ < 0) continue;
        float a = sL[w][h][j] * inv;
        float4 v4 = *(const float4*)&qkv[s_ * 768 + 512 + l * 4];
        a4.x += a * v4.x; a4.y += a * v4.y; a4.z += a * v4.z; a4.w += a * v4.w;
    }
    *(float4*)&qkv[i * 768 + l * 4] = a4;
}

// ---------------------------------------------------- fused score+pool+readout
// reads layer output from hi/lo fragments (x = b2f(h)+b2f(l) — identical to
// what the next GEMM's MFMA consumes).
__global__ __launch_bounds__(256) void spr_kernel(
    const unsigned short* __restrict__ Xh, const unsigned short* __restrict__ Xl,
    const float* __restrict__ w,
    float* __restrict__ score, int* __restrict__ nmask, float* __restrict__ acc)
{
    int g = blockIdx.x, t = threadIdx.x;
    int wv = t >> 6, l = t & 63;
    __shared__ float sW[256];
    __shared__ float sRaw[104];
    __shared__ float sFin[104];
    __shared__ int   sKeep[104];
    __shared__ float swn;
    __shared__ int cnt_s;
    if (t == 0) cnt_s = 0;
    sW[t] = w[t];
    __syncthreads();
    if (wv == 0) {
        float dw = 0.f;
        #pragma unroll
        for (int c = 0; c < 4; ++c) { float v = sW[l + c * 64]; dw += v * v; }
        #pragma unroll
        for (int o = 32; o > 0; o >>= 1) dw += __shfl_down(dw, o, 64);
        if (l == 0) swn = sqrtf(dw);
    }
    int base = g * S_NODES;
    for (int u = 0; u < 25; ++u) {
        int nl = wv * 25 + u;
        int row = base + nl;
        float dx = 0.f;
        #pragma unroll
        for (int c = 0; c < 4; ++c) {
            int cc = l + c * 64;
            int a = ((cc >> 3) * N_NODES + row) * 8 + (cc & 7);
            float xv = b2f(Xh[a]) + b2f(Xl[a]);
            dx += xv * sW[cc];
        }
        #pragma unroll
        for (int o = 32; o > 0; o >>= 1) dx += __shfl_down(dx, o, 64);
        if (l == 0) sRaw[nl] = dx;
    }
    __syncthreads();
    int alive = 0;
    float ck = -2.0f;
    if (t < S_NODES) {
        float sc = tanhf(sRaw[t] / swn);
        sFin[t] = sc;
        score[base + t] = sc;
        alive = nmask[base + t];
        ck = alive ? sc : -1.5f;
        sRaw[t] = ck;
        if (alive) atomicAdd(&cnt_s, 1);
    }
    __syncthreads();
    int k = (int)ceilf(0.8f * (float)cnt_s);
    if (t < S_NODES) {
        int rank = 0;
        for (int jj = 0; jj < S_NODES; ++jj) {
            float o = sRaw[jj];
            rank += (o > ck || (o == ck && jj < t)) ? 1 : 0;
        }
        int kp = (alive && rank < k) ? 1 : 0;
        sKeep[t] = kp;
        nmask[base + t] = kp;
    }
    __syncthreads();
    int tbase = ((t >> 3) * N_NODES) * 8 + (t & 7);
    float mx = NEGF, sm = 0.f, cnt = 0.f;
    for (int o = 0; o < S_NODES; o += 4) {
        int a0 = tbase + (base + o + 0) * 8;
        int a1 = tbase + (base + o + 1) * 8;
        int a2 = tbase + (base + o + 2) * 8;
        int a3 = tbase + (base + o + 3) * 8;
        float v0 = b2f(Xh[a0]) + b2f(Xl[a0]);
        float v1 = b2f(Xh[a1]) + b2f(Xl[a1]);
        float v2 = b2f(Xh[a2]) + b2f(Xl[a2]);
        float v3 = b2f(Xh[a3]) + b2f(Xl[a3]);
        if (sKeep[o + 0]) { float v = v0 * sFin[o + 0]; mx = fmaxf(mx, v); sm += v; cnt += 1.f; }
        if (sKeep[o + 1]) { float v = v1 * sFin[o + 1]; mx = fmaxf(mx, v); sm += v; cnt += 1.f; }
        if (sKeep[o + 2]) { float v = v2 * sFin[o + 2]; mx = fmaxf(mx, v); sm += v; cnt += 1.f; }
        if (sKeep[o + 3]) { float v = v3 * sFin[o + 3]; mx = fmaxf(mx, v); sm += v; cnt += 1.f; }
    }
    acc[(size_t)g * 512 + t] += mx;
    acc[(size_t)g * 512 + 256 + t] += sm / fmaxf(cnt, 1.f);
}

// ---------------------------------------------------------------- MLP head
__global__ __launch_bounds__(128) void mlp_kernel(
    const float* __restrict__ acc1, const float* __restrict__ acc2,
    const float* __restrict__ W1, const float* __restrict__ b1,
    const float* __restrict__ W2, const float* __restrict__ b2,
    const float* __restrict__ W3, const float* __restrict__ b3,
    float* __restrict__ out)
{
    int g = blockIdx.x, t = threadIdx.x;
    __shared__ float hrow[1024];
    __shared__ float h1s[128];
    __shared__ float h2s[64];
    __shared__ float o3[10];
    for (int j = t; j < 512; j += 128) {
        hrow[j] = acc1[(size_t)g * 512 + j];
        hrow[512 + j] = acc2[(size_t)g * 512 + j];
    }
    __syncthreads();
    float s = b1[t];
    for (int kx = 0; kx < 1024; ++kx) s += hrow[kx] * W1[(size_t)kx * 128 + t];
    h1s[t] = fmaxf(s, 0.f);
    __syncthreads();
    if (t < 64) {
        float s2 = b2[t];
        for (int kx = 0; kx < 128; ++kx) s2 += h1s[kx] * W2[kx * 64 + t];
        h2s[t] = fmaxf(s2, 0.f);
    }
    __syncthreads();
    if (t < 10) {
        float s3 = b3[t];
        for (int kx = 0; kx < 64; ++kx) s3 += h2s[kx] * W3[kx * 10 + t];
        o3[t] = s3;
    }
    __syncthreads();
    if (t < 10) {
        float m = o3[0];
        for (int j = 1; j < 10; ++j) m = fmaxf(m, o3[j]);
        float se = 0.f;
        for (int j = 0; j < 10; ++j) se += expf(o3[j] - m);
        out[g * 10 + t] = o3[t] - m - logf(se);
    }
}

// ---------------------------------------------------------------- launch
extern "C" void kernel_launch(void* const* d_in, const int* in_sizes, int n_in,
                              void* d_out, int out_size, void* d_ws, size_t ws_size,
                              hipStream_t stream) {
    (void)n_in; (void)out_size; (void)ws_size;
    const float* x0 = (const float*)d_in[0];
    const int* src = (const int*)d_in[1];
    const int* dst = src + N_EDGES;

    bool dictOrder = (in_sizes[7] == 64 * 768);
    const float *gatW[3], *gatAtt[3], *gatB[3], *gatRes[3];
    const float *gtWqkv[3], *gtBqkv[3], *gtWskip[3], *gtBskip[3];
    const float *gatPool, *gtPool;
    if (dictOrder) {
        for (int l = 0; l < 3; ++l) {
            int b = 3 + l * 8;
            gatW[l]    = (const float*)d_in[b + 0];
            gatAtt[l]  = (const float*)d_in[b + 1];
            gatB[l]    = (const float*)d_in[b + 2];
            gatRes[l]  = (const float*)d_in[b + 3];
            gtWqkv[l]  = (const float*)d_in[b + 4];
            gtBqkv[l]  = (const float*)d_in[b + 5];
            gtWskip[l] = (const float*)d_in[b + 6];
            gtBskip[l] = (const float*)d_in[b + 7];
        }
        gatPool = (const float*)d_in[27];
        gtPool  = (const float*)d_in[28];
    } else {
        for (int l = 0; l < 3; ++l) {
            int b = 3 + l * 4;
            gatW[l]   = (const float*)d_in[b + 0];
            gatAtt[l] = (const float*)d_in[b + 1];
            gatB[l]   = (const float*)d_in[b + 2];
            gatRes[l] = (const float*)d_in[b + 3];
            int c = 16 + l * 4;
            gtWqkv[l]  = (const float*)d_in[c + 0];
            gtBqkv[l]  = (const float*)d_in[c + 1];
            gtWskip[l] = (const float*)d_in[c + 2];
            gtBskip[l] = (const float*)d_in[c + 3];
        }
        gatPool = (const float*)d_in[15];
        gtPool  = (const float*)d_in[28];
    }
    const float* lin1W = (const float*)d_in[29];
    const float* lin1b = (const float*)d_in[30];
    const float* lin2W = (const float*)d_in[31];
    const float* lin2b = (const float*)d_in[32];
    const float* lin3W = (const float*)d_in[33];
    const float* lin3b = (const float*)d_in[34];

    char* wsp = (char*)d_ws;
    size_t off = 0;
    auto carve = [&](size_t bytes) -> void* {
        void* p = wsp + off;
        off += (bytes + 255) & ~(size_t)255;
        return p;
    };
    float* bufH   = (float*)carve((size_t)N_NODES * 768 * 4);       // 157.3 MB
    unsigned short* Xh = (unsigned short*)carve((size_t)N_NODES * 256 * 2);  // 26.2 MB
    unsigned short* Xl = (unsigned short*)carve((size_t)N_NODES * 256 * 2);  // 26.2 MB
    float* aS     = (float*)carve((size_t)N_NODES * 4 * 4);
    float* aD     = (float*)carve((size_t)N_NODES * 4 * 4);
    float* scoreB = (float*)carve((size_t)N_NODES * 4);
    int* nmask    = (int*)carve((size_t)N_NODES * 4);
    int* deg      = (int*)carve((size_t)N_NODES * 4);
    int* rowStart = (int*)carve((size_t)(N_NODES + 1) * 4);
    int* cursor   = (int*)carve((size_t)N_NODES * 4);
    int* csrSrc   = (int*)carve((size_t)N_EDGES * 4);
    float* acc1   = (float*)carve((size_t)N_GRAPHS * 512 * 4);
    float* acc2   = (float*)carve((size_t)N_GRAPHS * 512 * 4);
    const int wElems = 884736;
    unsigned short* whBase = (unsigned short*)carve((size_t)wElems * 2);
    unsigned short* wlBase = (unsigned short*)carve((size_t)wElems * 2);
    float* ysec   = bufH + (size_t)N_NODES * HDF;   // spare 2nd third (GAT agg)

    // single packed weight-split launch
    unsigned short *WH[12], *WL[12];
    {
        WSplitPack pack;
        int o = 0, maxSz = 0;
        for (int l = 0; l < 3; ++l) {
            int fi = (l == 0) ? 64 : 256;
            int sz[4] = {fi * 256, fi * 256, fi * 768, fi * 256};
            const float* Wp[4] = {gatW[l], gatRes[l], gtWqkv[l], gtWskip[l]};
            int NCs[4] = {256, 256, 768, 256};
            for (int q = 0; q < 4; ++q) {
                int idx = l * 4 + q;
                WH[idx] = whBase + o;
                WL[idx] = wlBase + o;
                pack.d[idx] = {Wp[q], WH[idx], WL[idx], fi, NCs[q]};
                if (sz[q] > maxSz) maxSz = sz[q];
                o += sz[q];
            }
        }
        wsplit_all<<<dim3((maxSz + 255) / 256, 12), 256, 0, stream>>>(pack);
    }

    init_zero<<<(N_GRAPHS * 512) / 256, 256, 0, stream>>>(deg, cursor, acc1, acc2);
    count_deg<<<N_EDGES / 256, 256, 0, stream>>>(dst, deg);
    scan_deg<<<1, 1024, 0, stream>>>(deg, rowStart);
    scatter_edges<<<N_EDGES / 256, 256, 0, stream>>>(src, dst, cursor, rowStart, csrSrc);

    for (int br = 0; br < 2; ++br) {
        bool isGAT = (br == 0);
        float* acc = isGAT ? acc1 : acc2;
        const float* poolW = isGAT ? gatPool : gtPool;
        set_int<<<N_NODES / 256, 256, 0, stream>>>(nmask, 1, N_NODES);
        asplit64<<<(N_NODES * 64) / 256, 256, 0, stream>>>(x0, Xh, Xl);
        int fi = 64;
        for (int l = 0; l < 3; ++l) {
            const float* rs = (l == 0) ? nullptr : scoreB;
            const int* rsm = (l == 0) ? nullptr : nmask;
            if (isGAT) {
                gemm_main<<<dim3(1, N_NODES / 128), 512, 0, stream>>>(
                    Xh, Xl, WH[l * 4 + 0], WL[l * 4 + 0], nullptr, bufH, fi, 256, rs, rsm);
                gat_att_pw<<<N_NODES / 4, 256, 0, stream>>>(bufH, gatAtt[l], aS, aD);
                gat_edge_pg<<<N_NODES / 4, 256, 0, stream>>>(bufH, aS, aD, rowStart,
                                                             csrSrc, nmask, ysec);
                gemm_fused<<<dim3(1, N_NODES / 128), 512, 0, stream>>>(
                    Xh, Xl, WH[l * 4 + 1], WL[l * 4 + 1], gatB[l], ysec, HDF,
                    nmask, fi, rs, rsm, Xh, Xl);
            } else {
                gemm_main<<<dim3(3, N_NODES / 128), 512, 0, stream>>>(
                    Xh, Xl, WH[l * 4 + 2], WL[l * 4 + 2], gtBqkv[l], bufH, fi, 768, rs, rsm);
                gt_edge_pg<<<N_NODES / 4, 256, 0, stream>>>(bufH, rowStart, csrSrc, nmask);
                gemm_fused<<<dim3(1, N_NODES / 128), 512, 0, stream>>>(
                    Xh, Xl, WH[l * 4 + 3], WL[l * 4 + 3], gtBskip[l], bufH /*q-slots*/, 768,
                    nmask, fi, rs, rsm, Xh, Xl);
            }
            spr_kernel<<<N_GRAPHS, 256, 0, stream>>>(Xh, Xl, poolW + l * HDF,
                                                     scoreB, nmask, acc);
            fi = HDF;
        }
    }
    mlp_kernel<<<N_GRAPHS, 128, 0, stream>>>(acc1, acc2, lin1W, lin1b, lin2W, lin2b,
                                             lin3W, lin3b, (float*)d_out);
}

// Round 16
// 1342.721 us; speedup vs baseline: 1.0521x; 1.0507x over previous
//
#include <hip/hip_runtime.h>
#include <hip/hip_bf16.h>
#include <math.h>

#define N_NODES 51200
#define N_GRAPHS 512
#define S_NODES 100
#define N_EDGES 512000
#define HDF 256          // H*D
#define NEGF (-1e30f)
#define DCAP 128         // per-node degree cap

typedef short bf16x8 __attribute__((ext_vector_type(8)));
typedef float f32x4 __attribute__((ext_vector_type(4)));

__device__ inline unsigned short f2b(float x) {   // fp32 -> bf16 RNE
    union { float f; unsigned u; } v; v.f = x;
    unsigned r = v.u + 0x7FFFu + ((v.u >> 16) & 1u);
    return (unsigned short)(r >> 16);
}
__device__ inline float b2f(unsigned short b) {
    union { float f; unsigned u; } v; v.u = ((unsigned)b) << 16; return v.f;
}

// ---------------------------------------------------------------- util
__global__ void set_int(int* __restrict__ p, int v, int n) {
    int i = blockIdx.x * 256 + threadIdx.x;
    if (i < n) p[i] = v;
}

__global__ void init_zero(int* __restrict__ deg, int* __restrict__ cursor,
                          float* __restrict__ acc1, float* __restrict__ acc2) {
    int i = blockIdx.x * 256 + threadIdx.x;   // grid covers 262144
    if (i < N_NODES) { deg[i] = 0; cursor[i] = 0; }
    acc1[i] = 0.f;
    acc2[i] = 0.f;
}

// pre-split weights: fp32 W[K x NC] -> bf16 hi/lo in MFMA fragment layout
// element (k,c) -> [(k>>3)*NC + c]*8 + (k&7)
struct WSplitDesc { const float* W; unsigned short* Wh; unsigned short* Wl; int K, NC; };
struct WSplitPack { WSplitDesc d[12]; };
__global__ void wsplit_all(WSplitPack p) {
    WSplitDesc d = p.d[blockIdx.y];
    int idx = blockIdx.x * 256 + threadIdx.x;
    if (idx >= d.K * d.NC) return;
    int k = idx / d.NC, c = idx - k * d.NC;
    float v = d.W[idx];
    unsigned short h = f2b(v);
    int o = ((k >> 3) * d.NC + c) * 8 + (k & 7);
    d.Wh[o] = h;
    d.Wl[o] = f2b(v - b2f(h));
}

// ------------------------------------------------- split-bf16 MFMA GEMM (main)
// 256 threads / 4 waves, 128x128 tile (2x2 wave grid, 64x64/wave).
// Finer block granularity -> 8 blocks/CU resident (vs 4 for 8-wave blocks),
// kills the scheduling tail that held qkv at 33% occupancy.
// A staged via LDS (hi/lo bf16, top-k scale folded); B direct from pre-split
// global fragment layout. grid = (NC/128, rows/128).
__global__ __launch_bounds__(256) void gemm_main_128(
    const float* __restrict__ A,
    const unsigned short* __restrict__ Bh_g, const unsigned short* __restrict__ Bl_g,
    const float* __restrict__ bias, float* __restrict__ C,
    int K, int NC,
    const float* __restrict__ rowScale, const int* __restrict__ rsMask)
{
    __shared__ unsigned short Ah[4 * 128 * 8];   // [kg][row][j]
    __shared__ unsigned short Al[4 * 128 * 8];
    int row0 = blockIdx.y * 128, col0 = blockIdx.x * 128;
    int t = threadIdx.x;
    int lane = t & 63, w = t >> 6;
    int wr = w >> 1, wc = w & 1;          // 2 x 2 wave grid
    int l15 = lane & 15, l4 = lane >> 4;
    f32x4 acc[4][4];
    #pragma unroll
    for (int m = 0; m < 4; ++m)
        #pragma unroll
        for (int n = 0; n < 4; ++n) acc[m][n] = (f32x4){0.f, 0.f, 0.f, 0.f};

    int arow = t & 127, akg2 = t >> 7;    // A staging: 2 kg-groups per thread
    float ascale = 1.f;
    if (rowScale) ascale = rsMask[row0 + arow] ? rowScale[row0 + arow] : 0.f;

    for (int k0 = 0; k0 < K; k0 += 32) {
        // ---- stage A (fp32 -> hi/lo bf16), folded top-k row scale
        #pragma unroll
        for (int q = 0; q < 2; ++q) {
            int kg = akg2 * 2 + q;
            const float* ap = A + (size_t)(row0 + arow) * K + k0 + kg * 8;
            float4 a0 = *(const float4*)ap;
            float4 a1 = *(const float4*)(ap + 4);
            float av[8] = {a0.x, a0.y, a0.z, a0.w, a1.x, a1.y, a1.z, a1.w};
            int abase = (kg * 128 + arow) * 8;
            #pragma unroll
            for (int j = 0; j < 8; ++j) {
                float s = av[j] * ascale;
                unsigned short h = f2b(s);
                Ah[abase + j] = h;
                Al[abase + j] = f2b(s - b2f(h));
            }
        }
        __syncthreads();
        // ---- B fragments direct from global (pre-split fragment layout)
        bf16x8 bh[4], bl[4];
        size_t brow = (size_t)((k0 >> 3) + l4) * NC;
        #pragma unroll
        for (int n = 0; n < 4; ++n) {
            size_t gb = (brow + col0 + wc * 64 + n * 16 + l15) * 8;
            bh[n] = *(const bf16x8*)&Bh_g[gb];
            bl[n] = *(const bf16x8*)&Bl_g[gb];
        }
        #pragma unroll
        for (int m = 0; m < 4; ++m) {
            int idx = (l4 * 128 + wr * 64 + m * 16 + l15) * 8;
            bf16x8 ah = *(bf16x8*)&Ah[idx];
            bf16x8 al = *(bf16x8*)&Al[idx];
            #pragma unroll
            for (int n = 0; n < 4; ++n) {
                acc[m][n] = __builtin_amdgcn_mfma_f32_16x16x32_bf16(ah, bh[n], acc[m][n], 0, 0, 0);
                acc[m][n] = __builtin_amdgcn_mfma_f32_16x16x32_bf16(ah, bl[n], acc[m][n], 0, 0, 0);
                acc[m][n] = __builtin_amdgcn_mfma_f32_16x16x32_bf16(al, bh[n], acc[m][n], 0, 0, 0);
            }
        }
        __syncthreads();
    }
    // ---- epilogue
    #pragma unroll
    for (int m = 0; m < 4; ++m) {
        #pragma unroll
        for (int n = 0; n < 4; ++n) {
            int col = col0 + wc * 64 + n * 16 + l15;
            float bv = bias ? bias[col] : 0.f;
            #pragma unroll
            for (int r = 0; r < 4; ++r) {
                int row = row0 + wr * 64 + m * 16 + l4 * 4 + r;
                C[(size_t)row * NC + col] = acc[m][n][r] + bv;
            }
        }
    }
}

// ------------------------------------------------- fused skip-GEMM (r11 form)
// 512 thr, 128x256 tile; grid.x == 1 (block owns full rows -> in-place safe).
// out = relu((diag(s)A)@B + agg + bias) * nmask, out stride 256.
__global__ __launch_bounds__(512) void mfma_gemm(
    const float* __restrict__ A,
    const unsigned short* __restrict__ Bh_g, const unsigned short* __restrict__ Bl_g,
    const float* __restrict__ bias, float* __restrict__ C,
    int K, int NC,
    const float* __restrict__ agg, int aggStride,
    const int* __restrict__ nmaskArr,
    const float* __restrict__ rowScale, const int* __restrict__ rsMask)
{
    __shared__ unsigned short Ah[4 * 128 * 8];   // [kg][row][j]
    __shared__ unsigned short Al[4 * 128 * 8];
    int row0 = blockIdx.y * 128, col0 = blockIdx.x * 256;
    int t = threadIdx.x;
    int lane = t & 63, w = t >> 6;
    int wr = w >> 2, wc = w & 3;          // 2 x 4 wave grid
    int l15 = lane & 15, l4 = lane >> 4;
    f32x4 acc[4][4];
    #pragma unroll
    for (int m = 0; m < 4; ++m)
        #pragma unroll
        for (int n = 0; n < 4; ++n) acc[m][n] = (f32x4){0.f, 0.f, 0.f, 0.f};

    int arow = t & 127, akg = t >> 7;     // A staging task (row, kgroup)
    float ascale = 1.f;
    if (rowScale) ascale = rsMask[row0 + arow] ? rowScale[row0 + arow] : 0.f;

    for (int k0 = 0; k0 < K; k0 += 32) {
        const float* ap = A + (size_t)(row0 + arow) * K + k0 + akg * 8;
        float4 a0 = *(const float4*)ap;
        float4 a1 = *(const float4*)(ap + 4);
        float av[8] = {a0.x, a0.y, a0.z, a0.w, a1.x, a1.y, a1.z, a1.w};
        int abase = (akg * 128 + arow) * 8;
        #pragma unroll
        for (int j = 0; j < 8; ++j) {
            float s = av[j] * ascale;
            unsigned short h = f2b(s);
            Ah[abase + j] = h;
            Al[abase + j] = f2b(s - b2f(h));
        }
        __syncthreads();
        bf16x8 bh[4], bl[4];
        size_t brow = (size_t)((k0 >> 3) + l4) * NC;
        #pragma unroll
        for (int n = 0; n < 4; ++n) {
            size_t gb = (brow + col0 + wc * 64 + n * 16 + l15) * 8;
            bh[n] = *(const bf16x8*)&Bh_g[gb];
            bl[n] = *(const bf16x8*)&Bl_g[gb];
        }
        #pragma unroll
        for (int m = 0; m < 4; ++m) {
            int idx = (l4 * 128 + wr * 64 + m * 16 + l15) * 8;
            bf16x8 ah = *(bf16x8*)&Ah[idx];
            bf16x8 al = *(bf16x8*)&Al[idx];
            #pragma unroll
            for (int n = 0; n < 4; ++n) {
                acc[m][n] = __builtin_amdgcn_mfma_f32_16x16x32_bf16(ah, bh[n], acc[m][n], 0, 0, 0);
                acc[m][n] = __builtin_amdgcn_mfma_f32_16x16x32_bf16(ah, bl[n], acc[m][n], 0, 0, 0);
                acc[m][n] = __builtin_amdgcn_mfma_f32_16x16x32_bf16(al, bh[n], acc[m][n], 0, 0, 0);
            }
        }
        __syncthreads();
    }
    bool fused = (agg != nullptr);
    #pragma unroll
    for (int m = 0; m < 4; ++m) {
        #pragma unroll
        for (int n = 0; n < 4; ++n) {
            int col = col0 + wc * 64 + n * 16 + l15;
            float bv = bias ? bias[col] : 0.f;
            #pragma unroll
            for (int r = 0; r < 4; ++r) {
                int row = row0 + wr * 64 + m * 16 + l4 * 4 + r;
                float v = acc[m][n][r] + bv;
                if (fused) {
                    v += agg[(size_t)row * aggStride + col];
                    float nm = nmaskArr[row] ? 1.f : 0.f;
                    C[(size_t)row * 256 + col] = fmaxf(v, 0.f) * nm;
                } else {
                    C[(size_t)row * NC + col] = v;
                }
            }
        }
    }
}

// ---------------------------------------------------------------- CSR build
__global__ void count_deg(const int* __restrict__ dst, int* __restrict__ deg) {
    int e = blockIdx.x * 256 + threadIdx.x;
    atomicAdd(&deg[dst[e]], 1);
}

__global__ __launch_bounds__(1024) void scan_deg(const int* __restrict__ deg,
                                                 int* __restrict__ rowStart) {
    __shared__ int part[1024];
    int t = threadIdx.x;
    const int chunk = N_NODES / 1024;      // 50
    int s = t * chunk;
    int sum = 0;
    for (int i = 0; i < chunk; ++i) sum += deg[s + i];
    part[t] = sum;
    __syncthreads();
    for (int d = 1; d < 1024; d <<= 1) {
        int v = (t >= d) ? part[t - d] : 0;
        __syncthreads();
        part[t] += v;
        __syncthreads();
    }
    int excl = (t == 0) ? 0 : part[t - 1];
    for (int i = 0; i < chunk; ++i) { rowStart[s + i] = excl; excl += deg[s + i]; }
    if (t == 1023) rowStart[N_NODES] = part[1023];
}

__global__ void scatter_edges(const int* __restrict__ src, const int* __restrict__ dst,
                              int* __restrict__ cursor, const int* __restrict__ rowStart,
                              int* __restrict__ csrSrc) {
    int e = blockIdx.x * 256 + threadIdx.x;
    int d = dst[e];
    int p = atomicAdd(&cursor[d], 1);
    csrSrc[rowStart[d] + p] = src[e];
}

// ---------------------------------------------------------------- GAT pieces
__global__ __launch_bounds__(256) void gat_att_pw(const float* __restrict__ hfeat,
                                                  const float* __restrict__ att,
                                                  float* __restrict__ aS,
                                                  float* __restrict__ aD) {
    int t = threadIdx.x, w = t >> 6, l = t & 63;
    int i = blockIdx.x * 4 + w;
    int h = l >> 4, g16 = l & 15;
    float4 hv = *(const float4*)&hfeat[i * HDF + l * 4];
    float4 a0 = *(const float4*)&att[l * 4];
    float4 a1 = *(const float4*)&att[256 + l * 4];
    float p0 = hv.x * a0.x + hv.y * a0.y + hv.z * a0.z + hv.w * a0.w;
    float p1 = hv.x * a1.x + hv.y * a1.y + hv.z * a1.z + hv.w * a1.w;
    p0 += __shfl_xor(p0, 1, 64);  p1 += __shfl_xor(p1, 1, 64);
    p0 += __shfl_xor(p0, 2, 64);  p1 += __shfl_xor(p1, 2, 64);
    p0 += __shfl_xor(p0, 4, 64);  p1 += __shfl_xor(p1, 4, 64);
    p0 += __shfl_xor(p0, 8, 64);  p1 += __shfl_xor(p1, 8, 64);
    if (g16 == 0) { aS[i * 4 + h] = p0; aD[i * 4 + h] = p1; }
}

// GAT aggregation: 1 node per wave, XCD-streamed; parallel sS preload;
// (head, edge)-parallel logits. edge mask == nmask[src]; self-loop appended.
__global__ __launch_bounds__(256) void gat_edge_pg(
    const float* __restrict__ hfeat, const float* __restrict__ aS, const float* __restrict__ aD,
    const int* __restrict__ rowStart, const int* __restrict__ csrSrc,
    const int* __restrict__ nmask,
    float* __restrict__ aggOut)
{
    int bid = blockIdx.x;
    int t = threadIdx.x, w = t >> 6, l = t & 63;
    int i = (bid & 7) * (N_NODES / 8) + (bid >> 3) * 4 + w;   // XCD-streamed
    int h = l >> 4, g16 = l & 15;
    __shared__ float sL[4][4][DCAP + 8];
    __shared__ int   sS[4][DCAP + 8];
    if (!nmask[i]) {
        *(float4*)&aggOut[i * HDF + l * 4] = make_float4(0.f, 0.f, 0.f, 0.f);
        return;
    }
    int rs = rowStart[i];
    int deg = min(rowStart[i + 1] - rs, DCAP);
    for (int j = l; j < deg; j += 64) {
        int s_ = csrSrc[rs + j];
        sS[w][j] = nmask[s_] ? s_ : -1;
    }
    if (l == 0) sS[w][deg] = i;            // self loop (node alive here)
    float adh = aD[i * 4 + h];
    for (int j = g16; j < deg; j += 16) {
        int s_ = sS[w][j];
        float lg = NEGF;
        if (s_ >= 0) {
            lg = aS[s_ * 4 + h] + adh;
            lg = (lg >= 0.f) ? lg : 0.2f * lg;
        }
        sL[w][h][j] = lg;
    }
    if (g16 == (deg & 15)) {               // self-loop logit, one lane per head
        float lg = aS[i * 4 + h] + adh;
        sL[w][h][deg] = (lg >= 0.f) ? lg : 0.2f * lg;
    }
    int tot = deg + 1;
    float m = NEGF;
    for (int j = g16; j < tot; j += 16) m = fmaxf(m, sL[w][h][j]);
    m = fmaxf(m, __shfl_xor(m, 1, 64));
    m = fmaxf(m, __shfl_xor(m, 2, 64));
    m = fmaxf(m, __shfl_xor(m, 4, 64));
    m = fmaxf(m, __shfl_xor(m, 8, 64));
    float sum = 0.f;
    for (int j = g16; j < tot; j += 16) {
        float lv = sL[w][h][j];
        float e = (lv > -1e29f) ? __expf(lv - m) : 0.f;
        sL[w][h][j] = e;
        sum += e;
    }
    sum += __shfl_xor(sum, 1, 64);
    sum += __shfl_xor(sum, 2, 64);
    sum += __shfl_xor(sum, 4, 64);
    sum += __shfl_xor(sum, 8, 64);
    float inv = 1.f / fmaxf(sum, 1e-16f);
    float4 a4 = make_float4(0.f, 0.f, 0.f, 0.f);
    for (int j = 0; j < tot; ++j) {
        int s_ = sS[w][j];
        if (s_ < 0) continue;
        float a = sL[w][h][j] * inv;
        float4 v4 = *(const float4*)&hfeat[s_ * HDF + l * 4];
        a4.x += a * v4.x; a4.y += a * v4.y; a4.z += a * v4.z; a4.w += a * v4.w;
    }
    *(float4*)&aggOut[i * HDF + l * 4] = a4;
}

// GT attention: 1 node per wave, XCD-streamed; parallel sS preload.
// qkv row: [q|k|v]; agg overwrites OWN q-slot (race-free).
__global__ __launch_bounds__(256) void gt_edge_pg(
    float* __restrict__ qkv,
    const int* __restrict__ rowStart, const int* __restrict__ csrSrc,
    const int* __restrict__ nmask)
{
    int bid = blockIdx.x;
    int t = threadIdx.x, w = t >> 6, l = t & 63;
    int i = (bid & 7) * (N_NODES / 8) + (bid >> 3) * 4 + w;   // XCD-streamed
    int h = l >> 4, g16 = l & 15;
    __shared__ float sL[4][4][DCAP + 8];
    __shared__ int   sS[4][DCAP + 8];
    if (!nmask[i]) {
        *(float4*)&qkv[i * 768 + l * 4] = make_float4(0.f, 0.f, 0.f, 0.f);
        return;
    }
    int rs = rowStart[i];
    int deg = min(rowStart[i + 1] - rs, DCAP);
    for (int j = l; j < deg; j += 64) {
        int s_ = csrSrc[rs + j];
        sS[w][j] = nmask[s_] ? s_ : -1;
    }
    float4 q4 = *(const float4*)&qkv[i * 768 + l * 4];
    for (int j = 0; j < deg; ++j) {
        int s_ = sS[w][j];
        float p = 0.f;
        if (s_ >= 0) {
            float4 k4 = *(const float4*)&qkv[s_ * 768 + 256 + l * 4];
            p = q4.x * k4.x + q4.y * k4.y + q4.z * k4.z + q4.w * k4.w;
        }
        p += __shfl_xor(p, 1, 64);
        p += __shfl_xor(p, 2, 64);
        p += __shfl_xor(p, 4, 64);
        p += __shfl_xor(p, 8, 64);
        if (g16 == 0) sL[w][h][j] = (s_ >= 0) ? p * 0.125f : NEGF;
    }
    float m = NEGF;
    for (int j = g16; j < deg; j += 16) m = fmaxf(m, sL[w][h][j]);
    m = fmaxf(m, __shfl_xor(m, 1, 64));
    m = fmaxf(m, __shfl_xor(m, 2, 64));
    m = fmaxf(m, __shfl_xor(m, 4, 64));
    m = fmaxf(m, __shfl_xor(m, 8, 64));
    float sum = 0.f;
    for (int j = g16; j < deg; j += 16) {
        float lv = sL[w][h][j];
        float e = (lv > -1e29f) ? __expf(lv - m) : 0.f;
        sL[w][h][j] = e;
        sum += e;
    }
    sum += __shfl_xor(sum, 1, 64);
    sum += __shfl_xor(sum, 2, 64);
    sum += __shfl_xor(sum, 4, 64);
    sum += __shfl_xor(sum, 8, 64);
    float inv = 1.f / fmaxf(sum, 1e-16f);
    float4 a4 = make_float4(0.f, 0.f, 0.f, 0.f);
    for (int j = 0; j < deg; ++j) {
        int s_ = sS[w][j];
        if (s_ < 0) continue;
        float a = sL[w][h][j] * inv;
        float4 v4 = *(const float4*)&qkv[s_ * 768 + 512 + l * 4];
        a4.x += a * v4.x; a4.y += a * v4.y; a4.z += a * v4.z; a4.w += a * v4.w;
    }
    *(float4*)&qkv[i * 768 + l * 4] = a4;
}

// ---------------------------------------------------- fused score+pool+readout
__global__ __launch_bounds__(256) void spr_kernel(
    const float* __restrict__ x, const float* __restrict__ w,
    float* __restrict__ score, int* __restrict__ nmask, float* __restrict__ acc)
{
    int g = blockIdx.x, t = threadIdx.x;
    int wv = t >> 6, l = t & 63;
    __shared__ float sW[256];
    __shared__ float sRaw[104];
    __shared__ float sFin[104];
    __shared__ int   sKeep[104];
    __shared__ float swn;
    __shared__ int cnt_s;
    if (t == 0) cnt_s = 0;
    sW[t] = w[t];
    __syncthreads();
    if (wv == 0) {
        float dw = 0.f;
        #pragma unroll
        for (int c = 0; c < 4; ++c) { float v = sW[l + c * 64]; dw += v * v; }
        #pragma unroll
        for (int o = 32; o > 0; o >>= 1) dw += __shfl_down(dw, o, 64);
        if (l == 0) swn = sqrtf(dw);
    }
    int base = g * S_NODES;
    for (int u = 0; u < 25; ++u) {
        int nl = wv * 25 + u;
        float dx = 0.f;
        #pragma unroll
        for (int c = 0; c < 4; ++c) {
            int cc = l + c * 64;
            dx += x[(size_t)(base + nl) * HDF + cc] * sW[cc];
        }
        #pragma unroll
        for (int o = 32; o > 0; o >>= 1) dx += __shfl_down(dx, o, 64);
        if (l == 0) sRaw[nl] = dx;
    }
    __syncthreads();
    int alive = 0;
    float ck = -2.0f;
    if (t < S_NODES) {
        float sc = tanhf(sRaw[t] / swn);
        sFin[t] = sc;
        score[base + t] = sc;
        alive = nmask[base + t];
        ck = alive ? sc : -1.5f;
        sRaw[t] = ck;
        if (alive) atomicAdd(&cnt_s, 1);
    }
    __syncthreads();
    int k = (int)ceilf(0.8f * (float)cnt_s);
    if (t < S_NODES) {
        int rank = 0;
        for (int jj = 0; jj < S_NODES; ++jj) {
            float o = sRaw[jj];
            rank += (o > ck || (o == ck && jj < t)) ? 1 : 0;
        }
        int kp = (alive && rank < k) ? 1 : 0;
        sKeep[t] = kp;
        nmask[base + t] = kp;
    }
    __syncthreads();
    float mx = NEGF, sm = 0.f, cnt = 0.f;
    for (int o = 0; o < S_NODES; o += 4) {
        float v0 = x[(size_t)(base + o + 0) * HDF + t];
        float v1 = x[(size_t)(base + o + 1) * HDF + t];
        float v2 = x[(size_t)(base + o + 2) * HDF + t];
        float v3 = x[(size_t)(base + o + 3) * HDF + t];
        if (sKeep[o + 0]) { float v = v0 * sFin[o + 0]; mx = fmaxf(mx, v); sm += v; cnt += 1.f; }
        if (sKeep[o + 1]) { float v = v1 * sFin[o + 1]; mx = fmaxf(mx, v); sm += v; cnt += 1.f; }
        if (sKeep[o + 2]) { float v = v2 * sFin[o + 2]; mx = fmaxf(mx, v); sm += v; cnt += 1.f; }
        if (sKeep[o + 3]) { float v = v3 * sFin[o + 3]; mx = fmaxf(mx, v); sm += v; cnt += 1.f; }
    }
    acc[(size_t)g * 512 + t] += mx;
    acc[(size_t)g * 512 + 256 + t] += sm / fmaxf(cnt, 1.f);
}

// ---------------------------------------------------------------- MLP head
__global__ __launch_bounds__(128) void mlp_kernel(
    const float* __restrict__ acc1, const float* __restrict__ acc2,
    const float* __restrict__ W1, const float* __restrict__ b1,
    const float* __restrict__ W2, const float* __restrict__ b2,
    const float* __restrict__ W3, const float* __restrict__ b3,
    float* __restrict__ out)
{
    int g = blockIdx.x, t = threadIdx.x;
    __shared__ float hrow[1024];
    __shared__ float h1s[128];
    __shared__ float h2s[64];
    __shared__ float o3[10];
    for (int j = t; j < 512; j += 128) {
        hrow[j] = acc1[(size_t)g * 512 + j];
        hrow[512 + j] = acc2[(size_t)g * 512 + j];
    }
    __syncthreads();
    float s = b1[t];
    for (int kx = 0; kx < 1024; ++kx) s += hrow[kx] * W1[(size_t)kx * 128 + t];
    h1s[t] = fmaxf(s, 0.f);
    __syncthreads();
    if (t < 64) {
        float s2 = b2[t];
        for (int kx = 0; kx < 128; ++kx) s2 += h1s[kx] * W2[kx * 64 + t];
        h2s[t] = fmaxf(s2, 0.f);
    }
    __syncthreads();
    if (t < 10) {
        float s3 = b3[t];
        for (int kx = 0; kx < 64; ++kx) s3 += h2s[kx] * W3[kx * 10 + t];
        o3[t] = s3;
    }
    __syncthreads();
    if (t < 10) {
        float m = o3[0];
        for (int j = 1; j < 10; ++j) m = fmaxf(m, o3[j]);
        float se = 0.f;
        for (int j = 0; j < 10; ++j) se += expf(o3[j] - m);
        out[g * 10 + t] = o3[t] - m - logf(se);
    }
}

// ---------------------------------------------------------------- launch
extern "C" void kernel_launch(void* const* d_in, const int* in_sizes, int n_in,
                              void* d_out, int out_size, void* d_ws, size_t ws_size,
                              hipStream_t stream) {
    (void)n_in; (void)out_size; (void)ws_size;
    const float* x0 = (const float*)d_in[0];
    const int* src = (const int*)d_in[1];
    const int* dst = src + N_EDGES;

    bool dictOrder = (in_sizes[7] == 64 * 768);
    const float *gatW[3], *gatAtt[3], *gatB[3], *gatRes[3];
    const float *gtWqkv[3], *gtBqkv[3], *gtWskip[3], *gtBskip[3];
    const float *gatPool, *gtPool;
    if (dictOrder) {
        for (int l = 0; l < 3; ++l) {
            int b = 3 + l * 8;
            gatW[l]    = (const float*)d_in[b + 0];
            gatAtt[l]  = (const float*)d_in[b + 1];
            gatB[l]    = (const float*)d_in[b + 2];
            gatRes[l]  = (const float*)d_in[b + 3];
            gtWqkv[l]  = (const float*)d_in[b + 4];
            gtBqkv[l]  = (const float*)d_in[b + 5];
            gtWskip[l] = (const float*)d_in[b + 6];
            gtBskip[l] = (const float*)d_in[b + 7];
        }
        gatPool = (const float*)d_in[27];
        gtPool  = (const float*)d_in[28];
    } else {
        for (int l = 0; l < 3; ++l) {
            int b = 3 + l * 4;
            gatW[l]   = (const float*)d_in[b + 0];
            gatAtt[l] = (const float*)d_in[b + 1];
            gatB[l]   = (const float*)d_in[b + 2];
            gatRes[l] = (const float*)d_in[b + 3];
            int c = 16 + l * 4;
            gtWqkv[l]  = (const float*)d_in[c + 0];
            gtBqkv[l]  = (const float*)d_in[c + 1];
            gtWskip[l] = (const float*)d_in[c + 2];
            gtBskip[l] = (const float*)d_in[c + 3];
        }
        gatPool = (const float*)d_in[15];
        gtPool  = (const float*)d_in[28];
    }
    const float* lin1W = (const float*)d_in[29];
    const float* lin1b = (const float*)d_in[30];
    const float* lin2W = (const float*)d_in[31];
    const float* lin2b = (const float*)d_in[32];
    const float* lin3W = (const float*)d_in[33];
    const float* lin3b = (const float*)d_in[34];

    char* wsp = (char*)d_ws;
    size_t off = 0;
    auto carve = [&](size_t bytes) -> void* {
        void* p = wsp + off;
        off += (bytes + 255) & ~(size_t)255;
        return p;
    };
    float* bufX   = (float*)carve((size_t)N_NODES * HDF * 4);   // 52.4 MB
    float* bufH   = (float*)carve((size_t)N_NODES * 768 * 4);   // 157.3 MB
    float* aS     = (float*)carve((size_t)N_NODES * 4 * 4);
    float* aD     = (float*)carve((size_t)N_NODES * 4 * 4);
    float* scoreB = (float*)carve((size_t)N_NODES * 4);
    int* nmask    = (int*)carve((size_t)N_NODES * 4);
    int* deg      = (int*)carve((size_t)N_NODES * 4);
    int* rowStart = (int*)carve((size_t)(N_NODES + 1) * 4);
    int* cursor   = (int*)carve((size_t)N_NODES * 4);
    int* csrSrc   = (int*)carve((size_t)N_EDGES * 4);
    float* acc1   = (float*)carve((size_t)N_GRAPHS * 512 * 4);
    float* acc2   = (float*)carve((size_t)N_GRAPHS * 512 * 4);
    const int wElems = 884736;
    unsigned short* whBase = (unsigned short*)carve((size_t)wElems * 2);
    unsigned short* wlBase = (unsigned short*)carve((size_t)wElems * 2);
    float* ysec   = bufH + (size_t)N_NODES * HDF;   // spare 2nd third of bufH (GAT agg)

    // single packed weight-split launch
    unsigned short *WH[12], *WL[12];
    {
        WSplitPack pack;
        int o = 0, maxSz = 0;
        for (int l = 0; l < 3; ++l) {
            int fi = (l == 0) ? 64 : 256;
            int sz[4] = {fi * 256, fi * 256, fi * 768, fi * 256};
            const float* Wp[4] = {gatW[l], gatRes[l], gtWqkv[l], gtWskip[l]};
            int NCs[4] = {256, 256, 768, 256};
            for (int q = 0; q < 4; ++q) {
                int idx = l * 4 + q;
                WH[idx] = whBase + o;
                WL[idx] = wlBase + o;
                pack.d[idx] = {Wp[q], WH[idx], WL[idx], fi, NCs[q]};
                if (sz[q] > maxSz) maxSz = sz[q];
                o += sz[q];
            }
        }
        wsplit_all<<<dim3((maxSz + 255) / 256, 12), 256, 0, stream>>>(pack);
    }

    init_zero<<<(N_GRAPHS * 512) / 256, 256, 0, stream>>>(deg, cursor, acc1, acc2);
    count_deg<<<N_EDGES / 256, 256, 0, stream>>>(dst, deg);
    scan_deg<<<1, 1024, 0, stream>>>(deg, rowStart);
    scatter_edges<<<N_EDGES / 256, 256, 0, stream>>>(src, dst, cursor, rowStart, csrSrc);

    for (int br = 0; br < 2; ++br) {
        bool isGAT = (br == 0);
        float* acc = isGAT ? acc1 : acc2;
        const float* poolW = isGAT ? gatPool : gtPool;
        set_int<<<N_NODES / 256, 256, 0, stream>>>(nmask, 1, N_NODES);
        const float* xcur = x0;
        int fi = 64;
        for (int l = 0; l < 3; ++l) {
            const float* rs = (l == 0) ? nullptr : scoreB;
            const int* rsm = (l == 0) ? nullptr : nmask;
            if (isGAT) {
                gemm_main_128<<<dim3(2, N_NODES / 128), 256, 0, stream>>>(
                    xcur, WH[l * 4 + 0], WL[l * 4 + 0], nullptr, bufH, fi, 256, rs, rsm);
                gat_att_pw<<<N_NODES / 4, 256, 0, stream>>>(bufH, gatAtt[l], aS, aD);
                gat_edge_pg<<<N_NODES / 4, 256, 0, stream>>>(bufH, aS, aD, rowStart,
                                                             csrSrc, nmask, ysec);
                mfma_gemm<<<dim3(1, N_NODES / 128), 512, 0, stream>>>(
                    xcur, WH[l * 4 + 1], WL[l * 4 + 1], gatB[l], bufX, fi, 256,
                    ysec, HDF, nmask, rs, rsm);
            } else {
                gemm_main_128<<<dim3(6, N_NODES / 128), 256, 0, stream>>>(
                    xcur, WH[l * 4 + 2], WL[l * 4 + 2], gtBqkv[l], bufH, fi, 768, rs, rsm);
                gt_edge_pg<<<N_NODES / 4, 256, 0, stream>>>(bufH, rowStart, csrSrc,
                                                            nmask);
                mfma_gemm<<<dim3(1, N_NODES / 128), 512, 0, stream>>>(
                    xcur, WH[l * 4 + 3], WL[l * 4 + 3], gtBskip[l], bufX, fi, 256,
                    bufH /*agg q-slots*/, 768, nmask, rs, rsm);
            }
            spr_kernel<<<N_GRAPHS, 256, 0, stream>>>(bufX, poolW + l * HDF,
                                                     scoreB, nmask, acc);
            xcur = bufX;
            fi = HDF;
        }
    }
    mlp_kernel<<<N_GRAPHS, 128, 0, stream>>>(acc1, acc2, lin1W, lin1b, lin2W, lin2b,
                                             lin3W, lin3b, (float*)d_out);
}

// Round 17
// 1199.762 us; speedup vs baseline: 1.1774x; 1.1192x over previous
//
#include <hip/hip_runtime.h>
#include <hip/hip_bf16.h>
#include <math.h>

#define N_NODES 51200
#define N_GRAPHS 512
#define S_NODES 100
#define N_EDGES 512000
#define HDF 256          // H*D
#define NEGF (-1e30f)
#define DCAP 128         // per-node degree cap

typedef short bf16x8 __attribute__((ext_vector_type(8)));
typedef float f32x4 __attribute__((ext_vector_type(4)));

__device__ inline unsigned short f2b(float x) {   // fp32 -> bf16 RNE
    union { float f; unsigned u; } v; v.f = x;
    unsigned r = v.u + 0x7FFFu + ((v.u >> 16) & 1u);
    return (unsigned short)(r >> 16);
}
__device__ inline float b2f(unsigned short b) {
    union { float f; unsigned u; } v; v.u = ((unsigned)b) << 16; return v.f;
}

// ---------------------------------------------------------------- util
__global__ void set_int(int* __restrict__ p, int v, int n) {
    int i = blockIdx.x * 256 + threadIdx.x;
    if (i < n) p[i] = v;
}

__global__ void init_zero(int* __restrict__ deg, int* __restrict__ cursor,
                          float* __restrict__ acc1, float* __restrict__ acc2) {
    int i = blockIdx.x * 256 + threadIdx.x;   // grid covers 262144
    if (i < N_NODES) { deg[i] = 0; cursor[i] = 0; }
    acc1[i] = 0.f;
    acc2[i] = 0.f;
}

// pre-split weights: fp32 W[K x NC] -> bf16 hi/lo in MFMA fragment layout
// element (k,c) -> [(k>>3)*NC + c]*8 + (k&7)
struct WSplitDesc { const float* W; unsigned short* Wh; unsigned short* Wl; int K, NC; };
struct WSplitPack { WSplitDesc d[12]; };
__global__ void wsplit_all(WSplitPack p) {
    WSplitDesc d = p.d[blockIdx.y];
    int idx = blockIdx.x * 256 + threadIdx.x;
    if (idx >= d.K * d.NC) return;
    int k = idx / d.NC, c = idx - k * d.NC;
    float v = d.W[idx];
    unsigned short h = f2b(v);
    int o = ((k >> 3) * d.NC + c) * 8 + (k & 7);
    d.Wh[o] = h;
    d.Wl[o] = f2b(v - b2f(h));
}

// ------------------------------------------------- split-bf16 MFMA GEMM (main)
// 64x256 tile, 256 threads / 4 waves (wave w = col quadrant, 64x64/wave).
// Row-split (NOT col-split, r16 lesson: col-split doubles A traffic): A traffic
// unchanged vs r11, but 2x finer block granularity + 1 staging task/thread
// (low VGPR) -> up to 8 blocks/CU resident vs 4. Math bit-identical to r11.
// grid = (NC/256, rows/64).
__global__ __launch_bounds__(256) void gemm_main64(
    const float* __restrict__ A,
    const unsigned short* __restrict__ Bh_g, const unsigned short* __restrict__ Bl_g,
    const float* __restrict__ bias, float* __restrict__ C,
    int K, int NC,
    const float* __restrict__ rowScale, const int* __restrict__ rsMask)
{
    __shared__ unsigned short Ah[4 * 64 * 8];   // [kg][row][j]
    __shared__ unsigned short Al[4 * 64 * 8];
    int row0 = blockIdx.y * 64, col0 = blockIdx.x * 256;
    int t = threadIdx.x;
    int lane = t & 63, wc = t >> 6;       // 1 x 4 wave grid (cols)
    int l15 = lane & 15, l4 = lane >> 4;
    f32x4 acc[4][4];
    #pragma unroll
    for (int m = 0; m < 4; ++m)
        #pragma unroll
        for (int n = 0; n < 4; ++n) acc[m][n] = (f32x4){0.f, 0.f, 0.f, 0.f};

    int arow = t & 63, akg = t >> 6;      // A staging: exactly 1 task/thread
    float ascale = 1.f;
    if (rowScale) ascale = rsMask[row0 + arow] ? rowScale[row0 + arow] : 0.f;

    for (int k0 = 0; k0 < K; k0 += 32) {
        // ---- stage A (fp32 -> hi/lo bf16), folded top-k row scale
        const float* ap = A + (size_t)(row0 + arow) * K + k0 + akg * 8;
        float4 a0 = *(const float4*)ap;
        float4 a1 = *(const float4*)(ap + 4);
        float av[8] = {a0.x, a0.y, a0.z, a0.w, a1.x, a1.y, a1.z, a1.w};
        int abase = (akg * 64 + arow) * 8;
        #pragma unroll
        for (int j = 0; j < 8; ++j) {
            float s = av[j] * ascale;
            unsigned short h = f2b(s);
            Ah[abase + j] = h;
            Al[abase + j] = f2b(s - b2f(h));
        }
        __syncthreads();
        // ---- B fragments direct from global (pre-split fragment layout)
        bf16x8 bh[4], bl[4];
        size_t brow = (size_t)((k0 >> 3) + l4) * NC;
        #pragma unroll
        for (int n = 0; n < 4; ++n) {
            size_t gb = (brow + col0 + wc * 64 + n * 16 + l15) * 8;
            bh[n] = *(const bf16x8*)&Bh_g[gb];
            bl[n] = *(const bf16x8*)&Bl_g[gb];
        }
        #pragma unroll
        for (int m = 0; m < 4; ++m) {
            int idx = (l4 * 64 + m * 16 + l15) * 8;
            bf16x8 ah = *(bf16x8*)&Ah[idx];
            bf16x8 al = *(bf16x8*)&Al[idx];
            #pragma unroll
            for (int n = 0; n < 4; ++n) {
                acc[m][n] = __builtin_amdgcn_mfma_f32_16x16x32_bf16(ah, bh[n], acc[m][n], 0, 0, 0);
                acc[m][n] = __builtin_amdgcn_mfma_f32_16x16x32_bf16(ah, bl[n], acc[m][n], 0, 0, 0);
                acc[m][n] = __builtin_amdgcn_mfma_f32_16x16x32_bf16(al, bh[n], acc[m][n], 0, 0, 0);
            }
        }
        __syncthreads();
    }
    // ---- epilogue
    #pragma unroll
    for (int m = 0; m < 4; ++m) {
        #pragma unroll
        for (int n = 0; n < 4; ++n) {
            int col = col0 + wc * 64 + n * 16 + l15;
            float bv = bias ? bias[col] : 0.f;
            #pragma unroll
            for (int r = 0; r < 4; ++r) {
                int row = row0 + m * 16 + l4 * 4 + r;
                C[(size_t)row * NC + col] = acc[m][n][r] + bv;
            }
        }
    }
}

// ------------------------------------------------- fused skip-GEMM, 64-row
// 64x256 tile, 4 waves; grid = (1, rows/64) -> block owns its 64 rows
// exclusively (reads A only from own rows) -> in-place over A safe.
// out = relu((diag(s)A)@B + agg + bias) * nmask, out stride 256.
__global__ __launch_bounds__(256) void gemm_fused64(
    const float* __restrict__ A,
    const unsigned short* __restrict__ Bh_g, const unsigned short* __restrict__ Bl_g,
    const float* __restrict__ bias, float* __restrict__ C,
    int K,
    const float* __restrict__ agg, int aggStride,
    const int* __restrict__ nmaskArr,
    const float* __restrict__ rowScale, const int* __restrict__ rsMask)
{
    const int NC = 256;
    __shared__ unsigned short Ah[4 * 64 * 8];
    __shared__ unsigned short Al[4 * 64 * 8];
    int row0 = blockIdx.y * 64;
    int t = threadIdx.x;
    int lane = t & 63, wc = t >> 6;
    int l15 = lane & 15, l4 = lane >> 4;
    f32x4 acc[4][4];
    #pragma unroll
    for (int m = 0; m < 4; ++m)
        #pragma unroll
        for (int n = 0; n < 4; ++n) acc[m][n] = (f32x4){0.f, 0.f, 0.f, 0.f};

    int arow = t & 63, akg = t >> 6;
    float ascale = 1.f;
    if (rowScale) ascale = rsMask[row0 + arow] ? rowScale[row0 + arow] : 0.f;

    for (int k0 = 0; k0 < K; k0 += 32) {
        const float* ap = A + (size_t)(row0 + arow) * K + k0 + akg * 8;
        float4 a0 = *(const float4*)ap;
        float4 a1 = *(const float4*)(ap + 4);
        float av[8] = {a0.x, a0.y, a0.z, a0.w, a1.x, a1.y, a1.z, a1.w};
        int abase = (akg * 64 + arow) * 8;
        #pragma unroll
        for (int j = 0; j < 8; ++j) {
            float s = av[j] * ascale;
            unsigned short h = f2b(s);
            Ah[abase + j] = h;
            Al[abase + j] = f2b(s - b2f(h));
        }
        __syncthreads();
        bf16x8 bh[4], bl[4];
        size_t brow = (size_t)((k0 >> 3) + l4) * NC;
        #pragma unroll
        for (int n = 0; n < 4; ++n) {
            size_t gb = (brow + wc * 64 + n * 16 + l15) * 8;
            bh[n] = *(const bf16x8*)&Bh_g[gb];
            bl[n] = *(const bf16x8*)&Bl_g[gb];
        }
        #pragma unroll
        for (int m = 0; m < 4; ++m) {
            int idx = (l4 * 64 + m * 16 + l15) * 8;
            bf16x8 ah = *(bf16x8*)&Ah[idx];
            bf16x8 al = *(bf16x8*)&Al[idx];
            #pragma unroll
            for (int n = 0; n < 4; ++n) {
                acc[m][n] = __builtin_amdgcn_mfma_f32_16x16x32_bf16(ah, bh[n], acc[m][n], 0, 0, 0);
                acc[m][n] = __builtin_amdgcn_mfma_f32_16x16x32_bf16(ah, bl[n], acc[m][n], 0, 0, 0);
                acc[m][n] = __builtin_amdgcn_mfma_f32_16x16x32_bf16(al, bh[n], acc[m][n], 0, 0, 0);
            }
        }
        __syncthreads();
    }
    #pragma unroll
    for (int m = 0; m < 4; ++m) {
        #pragma unroll
        for (int n = 0; n < 4; ++n) {
            int col = wc * 64 + n * 16 + l15;
            float bv = bias[col];
            #pragma unroll
            for (int r = 0; r < 4; ++r) {
                int row = row0 + m * 16 + l4 * 4 + r;
                float v = acc[m][n][r] + bv + agg[(size_t)row * aggStride + col];
                float nm = nmaskArr[row] ? 1.f : 0.f;
                C[(size_t)row * 256 + col] = fmaxf(v, 0.f) * nm;
            }
        }
    }
}

// ---------------------------------------------------------------- CSR build
__global__ void count_deg(const int* __restrict__ dst, int* __restrict__ deg) {
    int e = blockIdx.x * 256 + threadIdx.x;
    atomicAdd(&deg[dst[e]], 1);
}

__global__ __launch_bounds__(1024) void scan_deg(const int* __restrict__ deg,
                                                 int* __restrict__ rowStart) {
    __shared__ int part[1024];
    int t = threadIdx.x;
    const int chunk = N_NODES / 1024;      // 50
    int s = t * chunk;
    int sum = 0;
    for (int i = 0; i < chunk; ++i) sum += deg[s + i];
    part[t] = sum;
    __syncthreads();
    for (int d = 1; d < 1024; d <<= 1) {
        int v = (t >= d) ? part[t - d] : 0;
        __syncthreads();
        part[t] += v;
        __syncthreads();
    }
    int excl = (t == 0) ? 0 : part[t - 1];
    for (int i = 0; i < chunk; ++i) { rowStart[s + i] = excl; excl += deg[s + i]; }
    if (t == 1023) rowStart[N_NODES] = part[1023];
}

__global__ void scatter_edges(const int* __restrict__ src, const int* __restrict__ dst,
                              int* __restrict__ cursor, const int* __restrict__ rowStart,
                              int* __restrict__ csrSrc) {
    int e = blockIdx.x * 256 + threadIdx.x;
    int d = dst[e];
    int p = atomicAdd(&cursor[d], 1);
    csrSrc[rowStart[d] + p] = src[e];
}

// ---------------------------------------------------------------- GAT pieces
__global__ __launch_bounds__(256) void gat_att_pw(const float* __restrict__ hfeat,
                                                  const float* __restrict__ att,
                                                  float* __restrict__ aS,
                                                  float* __restrict__ aD) {
    int t = threadIdx.x, w = t >> 6, l = t & 63;
    int i = blockIdx.x * 4 + w;
    int h = l >> 4, g16 = l & 15;
    float4 hv = *(const float4*)&hfeat[i * HDF + l * 4];
    float4 a0 = *(const float4*)&att[l * 4];
    float4 a1 = *(const float4*)&att[256 + l * 4];
    float p0 = hv.x * a0.x + hv.y * a0.y + hv.z * a0.z + hv.w * a0.w;
    float p1 = hv.x * a1.x + hv.y * a1.y + hv.z * a1.z + hv.w * a1.w;
    p0 += __shfl_xor(p0, 1, 64);  p1 += __shfl_xor(p1, 1, 64);
    p0 += __shfl_xor(p0, 2, 64);  p1 += __shfl_xor(p1, 2, 64);
    p0 += __shfl_xor(p0, 4, 64);  p1 += __shfl_xor(p1, 4, 64);
    p0 += __shfl_xor(p0, 8, 64);  p1 += __shfl_xor(p1, 8, 64);
    if (g16 == 0) { aS[i * 4 + h] = p0; aD[i * 4 + h] = p1; }
}

// GAT aggregation: 1 node per wave, XCD-streamed; parallel sS preload;
// (head, edge)-parallel logits. edge mask == nmask[src]; self-loop appended.
__global__ __launch_bounds__(256) void gat_edge_pg(
    const float* __restrict__ hfeat, const float* __restrict__ aS, const float* __restrict__ aD,
    const int* __restrict__ rowStart, const int* __restrict__ csrSrc,
    const int* __restrict__ nmask,
    float* __restrict__ aggOut)
{
    int bid = blockIdx.x;
    int t = threadIdx.x, w = t >> 6, l = t & 63;
    int i = (bid & 7) * (N_NODES / 8) + (bid >> 3) * 4 + w;   // XCD-streamed
    int h = l >> 4, g16 = l & 15;
    __shared__ float sL[4][4][DCAP + 8];
    __shared__ int   sS[4][DCAP + 8];
    if (!nmask[i]) {
        *(float4*)&aggOut[i * HDF + l * 4] = make_float4(0.f, 0.f, 0.f, 0.f);
        return;
    }
    int rs = rowStart[i];
    int deg = min(rowStart[i + 1] - rs, DCAP);
    for (int j = l; j < deg; j += 64) {
        int s_ = csrSrc[rs + j];
        sS[w][j] = nmask[s_] ? s_ : -1;
    }
    if (l == 0) sS[w][deg] = i;            // self loop (node alive here)
    float adh = aD[i * 4 + h];
    for (int j = g16; j < deg; j += 16) {
        int s_ = sS[w][j];
        float lg = NEGF;
        if (s_ >= 0) {
            lg = aS[s_ * 4 + h] + adh;
            lg = (lg >= 0.f) ? lg : 0.2f * lg;
        }
        sL[w][h][j] = lg;
    }
    if (g16 == (deg & 15)) {               // self-loop logit, one lane per head
        float lg = aS[i * 4 + h] + adh;
        sL[w][h][deg] = (lg >= 0.f) ? lg : 0.2f * lg;
    }
    int tot = deg + 1;
    float m = NEGF;
    for (int j = g16; j < tot; j += 16) m = fmaxf(m, sL[w][h][j]);
    m = fmaxf(m, __shfl_xor(m, 1, 64));
    m = fmaxf(m, __shfl_xor(m, 2, 64));
    m = fmaxf(m, __shfl_xor(m, 4, 64));
    m = fmaxf(m, __shfl_xor(m, 8, 64));
    float sum = 0.f;
    for (int j = g16; j < tot; j += 16) {
        float lv = sL[w][h][j];
        float e = (lv > -1e29f) ? __expf(lv - m) : 0.f;
        sL[w][h][j] = e;
        sum += e;
    }
    sum += __shfl_xor(sum, 1, 64);
    sum += __shfl_xor(sum, 2, 64);
    sum += __shfl_xor(sum, 4, 64);
    sum += __shfl_xor(sum, 8, 64);
    float inv = 1.f / fmaxf(sum, 1e-16f);
    float4 a4 = make_float4(0.f, 0.f, 0.f, 0.f);
    for (int j = 0; j < tot; ++j) {
        int s_ = sS[w][j];
        if (s_ < 0) continue;
        float a = sL[w][h][j] * inv;
        float4 v4 = *(const float4*)&hfeat[s_ * HDF + l * 4];
        a4.x += a * v4.x; a4.y += a * v4.y; a4.z += a * v4.z; a4.w += a * v4.w;
    }
    *(float4*)&aggOut[i * HDF + l * 4] = a4;
}

// GT attention: 1 node per wave, XCD-streamed; parallel sS preload.
// qkv row: [q|k|v]; agg overwrites OWN q-slot (race-free).
__global__ __launch_bounds__(256) void gt_edge_pg(
    float* __restrict__ qkv,
    const int* __restrict__ rowStart, const int* __restrict__ csrSrc,
    const int* __restrict__ nmask)
{
    int bid = blockIdx.x;
    int t = threadIdx.x, w = t >> 6, l = t & 63;
    int i = (bid & 7) * (N_NODES / 8) + (bid >> 3) * 4 + w;   // XCD-streamed
    int h = l >> 4, g16 = l & 15;
    __shared__ float sL[4][4][DCAP + 8];
    __shared__ int   sS[4][DCAP + 8];
    if (!nmask[i]) {
        *(float4*)&qkv[i * 768 + l * 4] = make_float4(0.f, 0.f, 0.f, 0.f);
        return;
    }
    int rs = rowStart[i];
    int deg = min(rowStart[i + 1] - rs, DCAP);
    for (int j = l; j < deg; j += 64) {
        int s_ = csrSrc[rs + j];
        sS[w][j] = nmask[s_] ? s_ : -1;
    }
    float4 q4 = *(const float4*)&qkv[i * 768 + l * 4];
    for (int j = 0; j < deg; ++j) {
        int s_ = sS[w][j];
        float p = 0.f;
        if (s_ >= 0) {
            float4 k4 = *(const float4*)&qkv[s_ * 768 + 256 + l * 4];
            p = q4.x * k4.x + q4.y * k4.y + q4.z * k4.z + q4.w * k4.w;
        }
        p += __shfl_xor(p, 1, 64);
        p += __shfl_xor(p, 2, 64);
        p += __shfl_xor(p, 4, 64);
        p += __shfl_xor(p, 8, 64);
        if (g16 == 0) sL[w][h][j] = (s_ >= 0) ? p * 0.125f : NEGF;
    }
    float m = NEGF;
    for (int j = g16; j < deg; j += 16) m = fmaxf(m, sL[w][h][j]);
    m = fmaxf(m, __shfl_xor(m, 1, 64));
    m = fmaxf(m, __shfl_xor(m, 2, 64));
    m = fmaxf(m, __shfl_xor(m, 4, 64));
    m = fmaxf(m, __shfl_xor(m, 8, 64));
    float sum = 0.f;
    for (int j = g16; j < deg; j += 16) {
        float lv = sL[w][h][j];
        float e = (lv > -1e29f) ? __expf(lv - m) : 0.f;
        sL[w][h][j] = e;
        sum += e;
    }
    sum += __shfl_xor(sum, 1, 64);
    sum += __shfl_xor(sum, 2, 64);
    sum += __shfl_xor(sum, 4, 64);
    sum += __shfl_xor(sum, 8, 64);
    float inv = 1.f / fmaxf(sum, 1e-16f);
    float4 a4 = make_float4(0.f, 0.f, 0.f, 0.f);
    for (int j = 0; j < deg; ++j) {
        int s_ = sS[w][j];
        if (s_ < 0) continue;
        float a = sL[w][h][j] * inv;
        float4 v4 = *(const float4*)&qkv[s_ * 768 + 512 + l * 4];
        a4.x += a * v4.x; a4.y += a * v4.y; a4.z += a * v4.z; a4.w += a * v4.w;
    }
    *(float4*)&qkv[i * 768 + l * 4] = a4;
}

// ---------------------------------------------------- fused score+pool+readout
__global__ __launch_bounds__(256) void spr_kernel(
    const float* __restrict__ x, const float* __restrict__ w,
    float* __restrict__ score, int* __restrict__ nmask, float* __restrict__ acc)
{
    int g = blockIdx.x, t = threadIdx.x;
    int wv = t >> 6, l = t & 63;
    __shared__ float sW[256];
    __shared__ float sRaw[104];
    __shared__ float sFin[104];
    __shared__ int   sKeep[104];
    __shared__ float swn;
    __shared__ int cnt_s;
    if (t == 0) cnt_s = 0;
    sW[t] = w[t];
    __syncthreads();
    if (wv == 0) {
        float dw = 0.f;
        #pragma unroll
        for (int c = 0; c < 4; ++c) { float v = sW[l + c * 64]; dw += v * v; }
        #pragma unroll
        for (int o = 32; o > 0; o >>= 1) dw += __shfl_down(dw, o, 64);
        if (l == 0) swn = sqrtf(dw);
    }
    int base = g * S_NODES;
    for (int u = 0; u < 25; ++u) {
        int nl = wv * 25 + u;
        float dx = 0.f;
        #pragma unroll
        for (int c = 0; c < 4; ++c) {
            int cc = l + c * 64;
            dx += x[(size_t)(base + nl) * HDF + cc] * sW[cc];
        }
        #pragma unroll
        for (int o = 32; o > 0; o >>= 1) dx += __shfl_down(dx, o, 64);
        if (l == 0) sRaw[nl] = dx;
    }
    __syncthreads();
    int alive = 0;
    float ck = -2.0f;
    if (t < S_NODES) {
        float sc = tanhf(sRaw[t] / swn);
        sFin[t] = sc;
        score[base + t] = sc;
        alive = nmask[base + t];
        ck = alive ? sc : -1.5f;
        sRaw[t] = ck;
        if (alive) atomicAdd(&cnt_s, 1);
    }
    __syncthreads();
    int k = (int)ceilf(0.8f * (float)cnt_s);
    if (t < S_NODES) {
        int rank = 0;
        for (int jj = 0; jj < S_NODES; ++jj) {
            float o = sRaw[jj];
            rank += (o > ck || (o == ck && jj < t)) ? 1 : 0;
        }
        int kp = (alive && rank < k) ? 1 : 0;
        sKeep[t] = kp;
        nmask[base + t] = kp;
    }
    __syncthreads();
    float mx = NEGF, sm = 0.f, cnt = 0.f;
    for (int o = 0; o < S_NODES; o += 4) {
        float v0 = x[(size_t)(base + o + 0) * HDF + t];
        float v1 = x[(size_t)(base + o + 1) * HDF + t];
        float v2 = x[(size_t)(base + o + 2) * HDF + t];
        float v3 = x[(size_t)(base + o + 3) * HDF + t];
        if (sKeep[o + 0]) { float v = v0 * sFin[o + 0]; mx = fmaxf(mx, v); sm += v; cnt += 1.f; }
        if (sKeep[o + 1]) { float v = v1 * sFin[o + 1]; mx = fmaxf(mx, v); sm += v; cnt += 1.f; }
        if (sKeep[o + 2]) { float v = v2 * sFin[o + 2]; mx = fmaxf(mx, v); sm += v; cnt += 1.f; }
        if (sKeep[o + 3]) { float v = v3 * sFin[o + 3]; mx = fmaxf(mx, v); sm += v; cnt += 1.f; }
    }
    acc[(size_t)g * 512 + t] += mx;
    acc[(size_t)g * 512 + 256 + t] += sm / fmaxf(cnt, 1.f);
}

// ---------------------------------------------------------------- MLP head
__global__ __launch_bounds__(128) void mlp_kernel(
    const float* __restrict__ acc1, const float* __restrict__ acc2,
    const float* __restrict__ W1, const float* __restrict__ b1,
    const float* __restrict__ W2, const float* __restrict__ b2,
    const float* __restrict__ W3, const float* __restrict__ b3,
    float* __restrict__ out)
{
    int g = blockIdx.x, t = threadIdx.x;
    __shared__ float hrow[1024];
    __shared__ float h1s[128];
    __shared__ float h2s[64];
    __shared__ float o3[10];
    for (int j = t; j < 512; j += 128) {
        hrow[j] = acc1[(size_t)g * 512 + j];
        hrow[512 + j] = acc2[(size_t)g * 512 + j];
    }
    __syncthreads();
    float s = b1[t];
    for (int kx = 0; kx < 1024; ++kx) s += hrow[kx] * W1[(size_t)kx * 128 + t];
    h1s[t] = fmaxf(s, 0.f);
    __syncthreads();
    if (t < 64) {
        float s2 = b2[t];
        for (int kx = 0; kx < 128; ++kx) s2 += h1s[kx] * W2[kx * 64 + t];
        h2s[t] = fmaxf(s2, 0.f);
    }
    __syncthreads();
    if (t < 10) {
        float s3 = b3[t];
        for (int kx = 0; kx < 64; ++kx) s3 += h2s[kx] * W3[kx * 10 + t];
        o3[t] = s3;
    }
    __syncthreads();
    if (t < 10) {
        float m = o3[0];
        for (int j = 1; j < 10; ++j) m = fmaxf(m, o3[j]);
        float se = 0.f;
        for (int j = 0; j < 10; ++j) se += expf(o3[j] - m);
        out[g * 10 + t] = o3[t] - m - logf(se);
    }
}

// ---------------------------------------------------------------- launch
extern "C" void kernel_launch(void* const* d_in, const int* in_sizes, int n_in,
                              void* d_out, int out_size, void* d_ws, size_t ws_size,
                              hipStream_t stream) {
    (void)n_in; (void)out_size; (void)ws_size;
    const float* x0 = (const float*)d_in[0];
    const int* src = (const int*)d_in[1];
    const int* dst = src + N_EDGES;

    bool dictOrder = (in_sizes[7] == 64 * 768);
    const float *gatW[3], *gatAtt[3], *gatB[3], *gatRes[3];
    const float *gtWqkv[3], *gtBqkv[3], *gtWskip[3], *gtBskip[3];
    const float *gatPool, *gtPool;
    if (dictOrder) {
        for (int l = 0; l < 3; ++l) {
            int b = 3 + l * 8;
            gatW[l]    = (const float*)d_in[b + 0];
            gatAtt[l]  = (const float*)d_in[b + 1];
            gatB[l]    = (const float*)d_in[b + 2];
            gatRes[l]  = (const float*)d_in[b + 3];
            gtWqkv[l]  = (const float*)d_in[b + 4];
            gtBqkv[l]  = (const float*)d_in[b + 5];
            gtWskip[l] = (const float*)d_in[b + 6];
            gtBskip[l] = (const float*)d_in[b + 7];
        }
        gatPool = (const float*)d_in[27];
        gtPool  = (const float*)d_in[28];
    } else {
        for (int l = 0; l < 3; ++l) {
            int b = 3 + l * 4;
            gatW[l]   = (const float*)d_in[b + 0];
            gatAtt[l] = (const float*)d_in[b + 1];
            gatB[l]   = (const float*)d_in[b + 2];
            gatRes[l] = (const float*)d_in[b + 3];
            int c = 16 + l * 4;
            gtWqkv[l]  = (const float*)d_in[c + 0];
            gtBqkv[l]  = (const float*)d_in[c + 1];
            gtWskip[l] = (const float*)d_in[c + 2];
            gtBskip[l] = (const float*)d_in[c + 3];
        }
        gatPool = (const float*)d_in[15];
        gtPool  = (const float*)d_in[28];
    }
    const float* lin1W = (const float*)d_in[29];
    const float* lin1b = (const float*)d_in[30];
    const float* lin2W = (const float*)d_in[31];
    const float* lin2b = (const float*)d_in[32];
    const float* lin3W = (const float*)d_in[33];
    const float* lin3b = (const float*)d_in[34];

    char* wsp = (char*)d_ws;
    size_t off = 0;
    auto carve = [&](size_t bytes) -> void* {
        void* p = wsp + off;
        off += (bytes + 255) & ~(size_t)255;
        return p;
    };
    float* bufX   = (float*)carve((size_t)N_NODES * HDF * 4);   // 52.4 MB
    float* bufH   = (float*)carve((size_t)N_NODES * 768 * 4);   // 157.3 MB
    float* aS     = (float*)carve((size_t)N_NODES * 4 * 4);
    float* aD     = (float*)carve((size_t)N_NODES * 4 * 4);
    float* scoreB = (float*)carve((size_t)N_NODES * 4);
    int* nmask    = (int*)carve((size_t)N_NODES * 4);
    int* deg      = (int*)carve((size_t)N_NODES * 4);
    int* rowStart = (int*)carve((size_t)(N_NODES + 1) * 4);
    int* cursor   = (int*)carve((size_t)N_NODES * 4);
    int* csrSrc   = (int*)carve((size_t)N_EDGES * 4);
    float* acc1   = (float*)carve((size_t)N_GRAPHS * 512 * 4);
    float* acc2   = (float*)carve((size_t)N_GRAPHS * 512 * 4);
    const int wElems = 884736;
    unsigned short* whBase = (unsigned short*)carve((size_t)wElems * 2);
    unsigned short* wlBase = (unsigned short*)carve((size_t)wElems * 2);
    float* ysec   = bufH + (size_t)N_NODES * HDF;   // spare 2nd third of bufH (GAT agg)

    // single packed weight-split launch
    unsigned short *WH[12], *WL[12];
    {
        WSplitPack pack;
        int o = 0, maxSz = 0;
        for (int l = 0; l < 3; ++l) {
            int fi = (l == 0) ? 64 : 256;
            int sz[4] = {fi * 256, fi * 256, fi * 768, fi * 256};
            const float* Wp[4] = {gatW[l], gatRes[l], gtWqkv[l], gtWskip[l]};
            int NCs[4] = {256, 256, 768, 256};
            for (int q = 0; q < 4; ++q) {
                int idx = l * 4 + q;
                WH[idx] = whBase + o;
                WL[idx] = wlBase + o;
                pack.d[idx] = {Wp[q], WH[idx], WL[idx], fi, NCs[q]};
                if (sz[q] > maxSz) maxSz = sz[q];
                o += sz[q];
            }
        }
        wsplit_all<<<dim3((maxSz + 255) / 256, 12), 256, 0, stream>>>(pack);
    }

    init_zero<<<(N_GRAPHS * 512) / 256, 256, 0, stream>>>(deg, cursor, acc1, acc2);
    count_deg<<<N_EDGES / 256, 256, 0, stream>>>(dst, deg);
    scan_deg<<<1, 1024, 0, stream>>>(deg, rowStart);
    scatter_edges<<<N_EDGES / 256, 256, 0, stream>>>(src, dst, cursor, rowStart, csrSrc);

    for (int br = 0; br < 2; ++br) {
        bool isGAT = (br == 0);
        float* acc = isGAT ? acc1 : acc2;
        const float* poolW = isGAT ? gatPool : gtPool;
        set_int<<<N_NODES / 256, 256, 0, stream>>>(nmask, 1, N_NODES);
        const float* xcur = x0;
        int fi = 64;
        for (int l = 0; l < 3; ++l) {
            const float* rs = (l == 0) ? nullptr : scoreB;
            const int* rsm = (l == 0) ? nullptr : nmask;
            if (isGAT) {
                gemm_main64<<<dim3(1, N_NODES / 64), 256, 0, stream>>>(
                    xcur, WH[l * 4 + 0], WL[l * 4 + 0], nullptr, bufH, fi, 256, rs, rsm);
                gat_att_pw<<<N_NODES / 4, 256, 0, stream>>>(bufH, gatAtt[l], aS, aD);
                gat_edge_pg<<<N_NODES / 4, 256, 0, stream>>>(bufH, aS, aD, rowStart,
                                                             csrSrc, nmask, ysec);
                gemm_fused64<<<dim3(1, N_NODES / 64), 256, 0, stream>>>(
                    xcur, WH[l * 4 + 1], WL[l * 4 + 1], gatB[l], bufX, fi,
                    ysec, HDF, nmask, rs, rsm);
            } else {
                gemm_main64<<<dim3(3, N_NODES / 64), 256, 0, stream>>>(
                    xcur, WH[l * 4 + 2], WL[l * 4 + 2], gtBqkv[l], bufH, fi, 768, rs, rsm);
                gt_edge_pg<<<N_NODES / 4, 256, 0, stream>>>(bufH, rowStart, csrSrc,
                                                            nmask);
                gemm_fused64<<<dim3(1, N_NODES / 64), 256, 0, stream>>>(
                    xcur, WH[l * 4 + 3], WL[l * 4 + 3], gtBskip[l], bufX, fi,
                    bufH /*agg q-slots*/, 768, nmask, rs, rsm);
            }
            spr_kernel<<<N_GRAPHS, 256, 0, stream>>>(bufX, poolW + l * HDF,
                                                     scoreB, nmask, acc);
            xcur = bufX;
            fi = HDF;
        }
    }
    mlp_kernel<<<N_GRAPHS, 128, 0, stream>>>(acc1, acc2, lin1W, lin1b, lin2W, lin2b,
                                             lin3W, lin3b, (float*)d_out);
}